// Round 12
// baseline (96.659 us; speedup 1.0000x reference)
//
#include <hip/hip_runtime.h>
#include <math.h>

#define DIMN 1024
#define NH 16
#define HD 64
#define CHK 64
#define NB 2
#define SEQ 2048
#define NTOK (NB*SEQ)        // 4096
#define NCHUNK (SEQ/CHK)     // 32
#define GH 16

typedef __bf16 bf16x8 __attribute__((ext_vector_type(8)));
typedef float f32x4 __attribute__((ext_vector_type(4)));
typedef unsigned short u16x4 __attribute__((ext_vector_type(4)));

__device__ __forceinline__ unsigned short f2bf(float f) {
  union { float f; unsigned u; } a; a.f = f;
  unsigned r = a.u + 0x7FFFu + ((a.u >> 16) & 1u);
  return (unsigned short)(r >> 16);
}
__device__ __forceinline__ float bf2f(unsigned short v) {
  union { unsigned u; float f; } a; a.u = ((unsigned)v) << 16;
  return a.f;
}

__device__ __forceinline__ void gload16(const void* g, void* l) {
  __builtin_amdgcn_global_load_lds(
      (const __attribute__((address_space(1))) void*)g,
      (__attribute__((address_space(3))) void*)l, 16, 0, 0);
}

// ---- cast + transpose W (K x N f32) -> Wt (N x K bf16), LDS-tiled 64x64 ----
__global__ __launch_bounds__(256) void k_cast_wT(const float* __restrict__ W0,
    const float* __restrict__ W1, const float* __restrict__ W2,
    unsigned short* __restrict__ wt) {
  __shared__ float tile[64][68];
  int z = blockIdx.z;
  const float* W = z==0 ? W0 : z==1 ? W1 : W2;
  unsigned short* o = wt + (size_t)z*DIMN*DIMN;
  int k0 = blockIdx.y*64, n0 = blockIdx.x*64;
  int tr = threadIdx.x >> 4, c0 = (threadIdx.x & 15)*4;
  #pragma unroll
  for (int s = 0; s < 4; ++s) {
    int r = tr + s*16;
    *(f32x4*)&tile[r][c0] = *(const f32x4*)(W + (size_t)(k0+r)*DIMN + n0 + c0);
  }
  __syncthreads();
  #pragma unroll
  for (int s = 0; s < 4; ++s) {
    int nn = tr + s*16;
    ushort4 v;
    v.x = f2bf(tile[c0+0][nn]);
    v.y = f2bf(tile[c0+1][nn]);
    v.z = f2bf(tile[c0+2][nn]);
    v.w = f2bf(tile[c0+3][nn]);
    *(ushort4*)(o + (size_t)(n0+nn)*DIMN + k0 + c0) = v;
  }
}

// ---------------- transpose+cast Wg1 (1024x16 f32) -> wg1b (16x1024 bf16) ---
__global__ __launch_bounds__(256) void k_wg1t(const float* __restrict__ Wg1,
    unsigned short* __restrict__ wg1b) {
  int idx = blockIdx.x*256 + threadIdx.x;     // 16384
  int k = idx & 1023, j = idx >> 10;
  wg1b[j*DIMN + k] = f2bf(Wg1[k*GH + j]);
}

// ---- fused: cast x->bf16 (16-row tile via LDS) + hid = silu(xb@wg1b^T+bg1) --
__global__ __launch_bounds__(256) void k_castx_hidden(const float* __restrict__ x,
    const unsigned short* __restrict__ wg1b, const float* __restrict__ bg1,
    unsigned short* __restrict__ xb, float* __restrict__ hid) {
  __shared__ __align__(16) unsigned short xs[16][1032];  // pad: 2-way bank alias (free)
  __shared__ float red[4][16][16];
  int tid = threadIdx.x;
  size_t base = (size_t)blockIdx.x * 16 * DIMN;
  #pragma unroll
  for (int i = 0; i < 16; ++i) {
    int idx4 = tid + i*256;            // f32x4 index in tile, 0..4095
    int r = idx4 >> 8, c4 = idx4 & 255;
    f32x4 v = *(const f32x4*)(x + base + (size_t)idx4*4);
    u16x4 o;
    o[0]=f2bf(v[0]); o[1]=f2bf(v[1]); o[2]=f2bf(v[2]); o[3]=f2bf(v[3]);
    *(u16x4*)&xs[r][c4*4] = o;
    *(u16x4*)(xb + base + (size_t)idx4*4) = o;
  }
  __syncthreads();
  int l = tid & 63, w = tid >> 6;
  int lr = l & 15, kg = l >> 4;
  union FB { uint4 u; bf16x8 h; } a, b;
  f32x4 acc = {0.f,0.f,0.f,0.f};
  const unsigned short* wrow = wg1b + (size_t)lr*DIMN + w*256 + kg*8;
  #pragma unroll
  for (int kk = 0; kk < 8; ++kk) {
    a.u = *(const uint4*)&xs[lr][w*256 + kk*32 + kg*8];
    b.u = *(const uint4*)(wrow + kk*32);
    acc = __builtin_amdgcn_mfma_f32_16x16x32_bf16(a.h, b.h, acc, 0, 0, 0);
  }
  #pragma unroll
  for (int rg = 0; rg < 4; ++rg) red[w][kg*4 + rg][lr] = acc[rg];
  __syncthreads();
  {
    int m = tid >> 4, j = tid & 15;
    float s = red[0][m][j] + red[1][m][j] + red[2][m][j] + red[3][m][j];
    s += bg1[j];
    hid[(blockIdx.x*16 + m)*GH + j] = s / (1.f + expf(-s));   // silu
  }
}

// ---------------- fused bf16 MFMA projection: {q,k,v} = x @ [Wq|Wk|Wv] + b --
__global__ __launch_bounds__(256, 3) void k_projqkv(const unsigned short* __restrict__ xb,
    const unsigned short* __restrict__ wt,
    const float* __restrict__ b0, const float* __restrict__ b1, const float* __restrict__ b2,
    unsigned short* __restrict__ o0, unsigned short* __restrict__ o1,
    unsigned short* __restrict__ o2) {
  __shared__ unsigned short As[2][128*32];
  __shared__ unsigned short Bs[2][128*32];
  int tid = threadIdx.x;
  int wg = blockIdx.y * gridDim.x + blockIdx.x;   // 0..767 (768 % 8 == 0)
  int swz = (wg & 7) * 96 + (wg >> 3);
  int bx = swz % 24, by = swz / 24;
  int n3 = bx*128;
  int z = n3 >> 10;
  int n0l = n3 & 1023;
  const float* bias = z==0 ? b0 : z==1 ? b1 : b2;
  unsigned short* out = z==0 ? o0 : z==1 ? o1 : o2;
  int m0 = by*128;

  int l = tid & 63;
  int w = tid >> 6;
  int wr = w >> 1, wc = w & 1;
  int lrow = l & 15, kg = l >> 4;

  f32x4 acc[4][4] = {};

  int r0s = tid >> 2, s0s = tid & 3;
  int r1s = (tid + 256) >> 2;
  int sg0 = s0s ^ ((r0s >> 1) & 3);
  int sg1 = s0s ^ ((r1s >> 1) & 3);

  #define STAGE(buf, kt) do { \
    int kb_ = (kt)*32; \
    gload16(xb + ((size_t)(m0 + r0s)*DIMN + kb_ + sg0*8), &As[buf][tid*8]); \
    gload16(wt + ((size_t)(n3 + r0s)*DIMN + kb_ + sg0*8), &Bs[buf][tid*8]); \
    gload16(xb + ((size_t)(m0 + r1s)*DIMN + kb_ + sg1*8), &As[buf][(tid+256)*8]); \
    gload16(wt + ((size_t)(n3 + r1s)*DIMN + kb_ + sg1*8), &Bs[buf][(tid+256)*8]); \
  } while (0)

  STAGE(0, 0);
  int buf = 0;
  for (int t = 0; t < DIMN/32; ++t) {
    __syncthreads();
    if (t+1 < DIMN/32) STAGE(buf^1, t+1);
    union { uint4 u; bf16x8 h; } af[4], bfr[4];
    #pragma unroll
    for (int mf = 0; mf < 4; ++mf) {
      int r = wr*64 + mf*16 + lrow;
      int slot = kg ^ ((r >> 1) & 3);
      af[mf].u = *(const uint4*)&As[buf][r*32 + slot*8];
    }
    #pragma unroll
    for (int nf = 0; nf < 4; ++nf) {
      int r = wc*64 + nf*16 + lrow;
      int slot = kg ^ ((r >> 1) & 3);
      bfr[nf].u = *(const uint4*)&Bs[buf][r*32 + slot*8];
    }
    #pragma unroll
    for (int mf = 0; mf < 4; ++mf)
      #pragma unroll
      for (int nf = 0; nf < 4; ++nf)
        acc[mf][nf] = __builtin_amdgcn_mfma_f32_16x16x32_bf16(
            af[mf].h, bfr[nf].h, acc[mf][nf], 0, 0, 0);
    buf ^= 1;
  }
  #undef STAGE

  float bv[4];
  #pragma unroll
  for (int nf = 0; nf < 4; ++nf) bv[nf] = bias[n0l + wc*64 + nf*16 + lrow];
  #pragma unroll
  for (int mf = 0; mf < 4; ++mf) {
    int rbase = m0 + wr*64 + mf*16 + kg*4;
    #pragma unroll
    for (int nf = 0; nf < 4; ++nf) {
      int c = n0l + wc*64 + nf*16 + lrow;
      #pragma unroll
      for (int rg = 0; rg < 4; ++rg)
        out[(size_t)(rbase+rg)*DIMN + c] = f2bf(acc[mf][nf][rg] + bv[nf]);
    }
  }
}

// ---------------- pass 1a: per-chunk increment G_n via MFMA -----------------
__global__ __launch_bounds__(256, 3) void k_ginc(const unsigned short* __restrict__ kbuf,
    const unsigned short* __restrict__ vbuf,
    const float* __restrict__ hid, const float* __restrict__ Wg2,
    const float* __restrict__ bg2,
    unsigned short* __restrict__ G, float* __restrict__ Bv) {
  __shared__ __align__(16) unsigned short kb16[64*72];   // [i][d]
  __shared__ __align__(16) unsigned short vT[64*72];     // [e][i]
  __shared__ __align__(16) unsigned short kdT[64*72];    // [d][i]
  __shared__ __align__(16) float scr[2048];              // hid tile | Wg2 slice
  __shared__ float seg[4][64];
  int tid = threadIdx.x;
  int bid = blockIdx.x;                 // bh*NCHUNK + n
  int bh = bid >> 5, n = bid & 31;
  int b = bh >> 4, h = bh & 15;
  int colbase = h*HD;
  size_t rowbase = (size_t)b*SEQ + n*CHK;

  {
    int r = tid >> 2, j0 = (tid & 3)*4;
    *(f32x4*)&scr[r*16 + j0] = *(const f32x4*)(hid + (rowbase + r)*GH + j0);
    int j = tid >> 4, d0 = (tid & 15)*4;
    *(f32x4*)&scr[1024 + j*64 + d0] = *(const f32x4*)(Wg2 + (size_t)j*DIMN + colbase + d0);
  }
  #pragma unroll
  for (int i = 0; i < 4; ++i) {
    int f4 = tid + i*256;
    int r = f4 >> 4, cg = f4 & 15, c0 = cg*4;
    size_t g = (rowbase + r)*DIMN + colbase + c0;
    u16x4 k4 = *(const u16x4*)(kbuf + g);
    u16x4 v4 = *(const u16x4*)(vbuf + g);
    *(u16x4*)&kb16[r*72 + c0] = k4;
    #pragma unroll
    for (int j = 0; j < 4; ++j) vT[(c0+j)*72 + r] = v4[j];
  }
  __syncthreads();

  {
    int d = tid & 63, ig = tid >> 6;
    float wcol[16];
    #pragma unroll
    for (int j = 0; j < 16; ++j) wcol[j] = scr[1024 + j*64 + d];
    float bgd = bg2[colbase + d];
    float P[16];
    float run = 0.f;
    #pragma unroll
    for (int t = 0; t < 16; ++t) {
      int i = ig*16 + t;
      float acc = bgd;
      #pragma unroll
      for (int j = 0; j < 16; ++j) acc = fmaf(scr[i*16 + j], wcol[j], acc);
      float gg = 1.f/(1.f + expf(-acc));
      run += log2f(fmaf(0.9f, gg, 0.1f));
      P[t] = run;
    }
    seg[ig][d] = run;
    __syncthreads();
    float s0 = seg[0][d], s1 = seg[1][d], s2 = seg[2][d], s3 = seg[3][d];
    float carry = (ig > 0 ? s0 : 0.f) + (ig > 1 ? s1 : 0.f) + (ig > 2 ? s2 : 0.f);
    float Lb63 = s0 + s1 + s2 + s3;
    if (ig == 0) Bv[(size_t)bid*HD + d] = exp2f(Lb63);
    union { unsigned short s[16]; uint4 u[2]; } kd;
    #pragma unroll
    for (int t = 0; t < 16; ++t) {
      int i = ig*16 + t;
      float kv = bf2f(kb16[i*72 + d]);
      kd.s[t] = f2bf(kv * exp2f(Lb63 - carry - P[t]));   // suffix decay
    }
    *(uint4*)&kdT[d*72 + ig*16] = kd.u[0];
    *(uint4*)&kdT[d*72 + ig*16 + 8] = kd.u[1];
  }
  __syncthreads();

  int l = tid & 63, w = tid >> 6;
  int lr = l & 15, kg = l >> 4;
  int ks = kg*8;
  int arow = w*16 + lr;
  union FB { uint4 u; bf16x8 h; } a0, a1;
  a0.u = *(const uint4*)&kdT[arow*72 + ks];
  a1.u = *(const uint4*)&kdT[arow*72 + 32 + ks];
  unsigned short* gp = G + (size_t)bid*(HD*HD);
  #pragma unroll
  for (int nf = 0; nf < 4; ++nf) {
    FB b0v, b1v;
    b0v.u = *(const uint4*)&vT[(nf*16+lr)*72 + ks];
    b1v.u = *(const uint4*)&vT[(nf*16+lr)*72 + 32 + ks];
    f32x4 z = {0.f,0.f,0.f,0.f};
    z = __builtin_amdgcn_mfma_f32_16x16x32_bf16(a0.h, b0v.h, z, 0,0,0);
    z = __builtin_amdgcn_mfma_f32_16x16x32_bf16(a1.h, b1v.h, z, 0,0,0);
    #pragma unroll
    for (int rg = 0; rg < 4; ++rg)
      gp[(w*16 + kg*4 + rg)*HD + nf*16 + lr] = f2bf(z[rg]);
  }
}

// ---- pass 1b (parallel scan): preload-all then in-place bf16 G -> states ---
__global__ __launch_bounds__(256) void k_scan(unsigned short* __restrict__ buf,
    const float* __restrict__ Bv) {
  int idx = blockIdx.x*256 + threadIdx.x;   // 131072 = 32*64*64
  int e = idx & 63, d = (idx >> 6) & 63, bh = idx >> 12;
  unsigned short* gp = buf + (size_t)bh*NCHUNK*HD*HD + d*HD + e;
  const float* bp = Bv + (size_t)bh*NCHUNK*HD + d;
  float g[NCHUNK], bb[NCHUNK];
  #pragma unroll
  for (int n = 0; n < NCHUNK; ++n) g[n] = bf2f(gp[n*(HD*HD)]);
  #pragma unroll
  for (int n = 0; n < NCHUNK; ++n) bb[n] = bp[n*HD];
  float s = 0.f;
  #pragma unroll
  for (int n = 0; n < NCHUNK; ++n) {
    gp[n*(HD*HD)] = f2bf(s);
    s = fmaf(bb[n], s, g[n]);
  }
}

// ---------------- pass 2: MFMA per-chunk intra softmax + inter (sub=32) -----
// LDS diet (~45 KB -> 3 blocks/CU): q/k direct from global, single Swt buffer
// with split inter (waves 0,1 pre-commit; waves 2,3 post-commit), scr/seg/dgs
// aliased inside Pl, merged alpha+prefix (bit-identical lb).
__global__ __launch_bounds__(256, 3) void k_chunk(const unsigned short* __restrict__ qbuf,
    const unsigned short* __restrict__ kbuf, const unsigned short* __restrict__ vbuf,
    const float* __restrict__ hid, const float* __restrict__ Wg2,
    const float* __restrict__ bg2,
    const unsigned short* __restrict__ states, float* __restrict__ outp) {
  __shared__ __align__(16) unsigned short vT[4600];    // [e][s] stride 72
  __shared__ __align__(16) unsigned short Swt[4600];   // [e][d] stride 72; S0 then S1 in-place
  __shared__ __align__(16) unsigned short Pl[4608];    // P [i][s] stride 72; early scr/seg; inter dgs
  __shared__ __align__(16) float lb[4416];             // [i][d] stride 68 excl prefix; row 64 @ 64*68

  const int tid = threadIdx.x;
  const int bid = blockIdx.x;
  const int bh = bid >> 5, n = bid & 31;
  const int b = bh >> 4, h = bh & 15;
  const int colbase = h*HD;
  const size_t rowbase = (size_t)b*SEQ + n*CHK;
  const unsigned short* stp = states + (size_t)(bh*NCHUNK + n)*(HD*HD);

  float* scr = (float*)Pl;            // [0..1023] hid tile
  float* segp = scr + 1024;           // [4][64] prefix carries

  // ---- stage hid, v^T, S0 ----
  {
    int r = tid >> 2, j0 = (tid & 3)*4;
    *(f32x4*)&scr[r*16 + j0] = *(const f32x4*)(hid + (rowbase + r)*GH + j0);
  }
  #pragma unroll
  for (int i = 0; i < 4; ++i) {
    int f4 = tid + i*256;
    int r = f4 >> 4, cg = f4 & 15, c0 = cg*4;
    u16x4 v4 = *(const u16x4*)(vbuf + (rowbase + r)*DIMN + colbase + c0);
    u16x4 s4 = *(const u16x4*)(stp + r*HD + c0);
    #pragma unroll
    for (int j = 0; j < 4; ++j) {
      vT[(c0+j)*72 + r] = v4[j];
      Swt[(c0+j)*72 + r] = s4[j];
    }
  }
  __syncthreads();

  // ---- alpha + in-reg prefix: thread owns (d, ig); identical fma/log2 order
  {
    int d = tid & 63, ig = tid >> 6;
    float wcol[16];
    #pragma unroll
    for (int j = 0; j < 16; ++j) wcol[j] = Wg2[(size_t)j*DIMN + colbase + d];
    float bgd = bg2[colbase + d];
    float Pex[16];
    float run = 0.f;
    #pragma unroll
    for (int t = 0; t < 16; ++t) {
      int i = ig*16 + t;
      float acc = bgd;
      #pragma unroll
      for (int j = 0; j < 16; ++j) acc = fmaf(scr[i*16 + j], wcol[j], acc);
      float gg = 1.f/(1.f + expf(-acc));
      Pex[t] = run;
      run += log2f(fmaf(0.9f, gg, 0.1f));
    }
    segp[ig*64 + d] = run;
    __syncthreads();
    float carry = 0.f;
    for (int w2 = 0; w2 < ig; ++w2) carry += segp[w2*64 + d];
    #pragma unroll
    for (int t = 0; t < 16; ++t)
      lb[(ig*16 + t)*68 + d] = carry + Pex[t];
    if (ig == 3) lb[64*68 + d] = carry + run;
  }
  __syncthreads();

  const int l = tid & 63, w = tid >> 6;
  const int lr = l & 15, lg = l >> 4;
  const int ks = lg*8;
  const int arow = w*16 + lr;

  union FB { uint4 u; bf16x8 h; unsigned short s[8]; };

  // ---- QK^T (MFMA), q/k direct from global ----
  const unsigned short* qrow = qbuf + (rowbase + arow)*DIMN + colbase;
  FB qa0, qa1;
  qa0.u = *(const uint4*)(qrow + ks);
  qa1.u = *(const uint4*)(qrow + 32 + ks);
  f32x4 sc[4];
  #pragma unroll
  for (int nf = 0; nf < 4; ++nf) {
    const unsigned short* krow = kbuf + (rowbase + nf*16 + lr)*DIMN + colbase;
    FB b0, b1;
    b0.u = *(const uint4*)(krow + ks);
    b1.u = *(const uint4*)(krow + 32 + ks);
    f32x4 z = {0.f,0.f,0.f,0.f};
    z = __builtin_amdgcn_mfma_f32_16x16x32_bf16(qa0.h, b0.h, z, 0,0,0);
    z = __builtin_amdgcn_mfma_f32_16x16x32_bf16(qa1.h, b1.h, z, 0,0,0);
    sc[nf] = z;
  }

  // ---- in-register causal softmax ----
  float rmax[4] = {-3e38f,-3e38f,-3e38f,-3e38f};
  #pragma unroll
  for (int nf = 0; nf < 4; ++nf) {
    int col = nf*16 + lr;
    #pragma unroll
    for (int rg = 0; rg < 4; ++rg) {
      int row = w*16 + lg*4 + rg;
      float v = sc[nf][rg]*0.125f;
      if (col > row) v = -1e30f;
      sc[nf][rg] = v;
      rmax[rg] = fmaxf(rmax[rg], v);
    }
  }
  #pragma unroll
  for (int m = 1; m <= 8; m <<= 1)
    #pragma unroll
    for (int rg = 0; rg < 4; ++rg)
      rmax[rg] = fmaxf(rmax[rg], __shfl_xor(rmax[rg], m));
  float rsum[4] = {0.f,0.f,0.f,0.f};
  #pragma unroll
  for (int nf = 0; nf < 4; ++nf)
    #pragma unroll
    for (int rg = 0; rg < 4; ++rg) {
      float e = exp2f((sc[nf][rg] - rmax[rg])*1.44269504f);
      sc[nf][rg] = e;
      rsum[rg] += e;
    }
  #pragma unroll
  for (int m = 1; m <= 8; m <<= 1)
    #pragma unroll
    for (int rg = 0; rg < 4; ++rg)
      rsum[rg] += __shfl_xor(rsum[rg], m);
  #pragma unroll
  for (int nf = 0; nf < 4; ++nf)
    #pragma unroll
    for (int rg = 0; rg < 4; ++rg)
      Pl[(w*16 + lg*4 + rg)*72 + nf*16 + lr] = f2bf(sc[nf][rg]);
  float inv[4];
  #pragma unroll
  for (int rg = 0; rg < 4; ++rg) inv[rg] = 1.f/rsum[rg];
  __syncthreads();

  // ---- intra = P@V / rowsum (MFMA) ----
  f32x4 acc[4];
  {
    FB p0, p1;
    p0.u = *(const uint4*)&Pl[arow*72 + ks];
    p1.u = *(const uint4*)&Pl[arow*72 + 32 + ks];
    #pragma unroll
    for (int nf = 0; nf < 4; ++nf) {
      FB v0, v1;
      v0.u = *(const uint4*)&vT[(nf*16+lr)*72 + ks];
      v1.u = *(const uint4*)&vT[(nf*16+lr)*72 + 32 + ks];
      f32x4 z = {0.f,0.f,0.f,0.f};
      z = __builtin_amdgcn_mfma_f32_16x16x32_bf16(p0.h, v0.h, z, 0,0,0);
      z = __builtin_amdgcn_mfma_f32_16x16x32_bf16(p1.h, v1.h, z, 0,0,0);
      #pragma unroll
      for (int rg = 0; rg < 4; ++rg)
        acc[nf][rg] = z[rg]*inv[rg];
    }
  }

  // ---- state update into regs: S1 = diag(exp2(lb32)) S0 + K^T_dec V --------
  u16x4 s1v[4];
  {
    int dA = arow;
    float lb32 = lb[32*68 + dA];
    FB ku;
    #pragma unroll
    for (int j = 0; j < 8; ++j) {
      int s = ks + j;
      float kv = bf2f(kbuf[(rowbase + s)*DIMN + colbase + dA]);
      ku.s[j] = f2bf(kv * exp2f(lb32 - lb[(s+1)*68 + dA]));
    }
    int d0 = w*16 + lg*4;
    float bs[4];
    #pragma unroll
    for (int rg = 0; rg < 4; ++rg) bs[rg] = exp2f(lb[32*68 + d0 + rg]);
    #pragma unroll
    for (int nf = 0; nf < 4; ++nf) {
      int e = nf*16 + lr;
      FB vv;
      vv.u = *(const uint4*)&vT[e*72 + ks];
      f32x4 z = {0.f,0.f,0.f,0.f};
      z = __builtin_amdgcn_mfma_f32_16x16x32_bf16(ku.h, vv.h, z, 0,0,0);
      u16x4 s0v = *(const u16x4*)&Swt[e*72 + d0];
      #pragma unroll
      for (int rg = 0; rg < 4; ++rg)
        s1v[nf][rg] = f2bf(z[rg] + bs[rg]*bf2f(s0v[rg]));
    }
  }
  __syncthreads();   // all PV Pl-reads + Swt(S0) state-reads done

  // ---- inter body: cross (qdec @ S^T) + strict-lower diag ----
  unsigned short* dgs = Pl;            // aliased over dead P (own-wave region)
  auto do_inter = [&](int T) {
    FB qd[2];
    #pragma unroll
    for (int kst = 0; kst < 2; ++kst) {
      int ds = kst*32 + ks;
      f32x4 lbi0 = *(const f32x4*)&lb[arow*68 + ds];
      f32x4 lbi1 = *(const f32x4*)&lb[arow*68 + ds + 4];
      f32x4 lbt0 = *(const f32x4*)&lb[T*68 + ds];
      f32x4 lbt1 = *(const f32x4*)&lb[T*68 + ds + 4];
      FB qr = (kst == 0) ? qa0 : qa1;
      #pragma unroll
      for (int j = 0; j < 4; ++j) {
        qd[kst].s[j]   = f2bf(bf2f(qr.s[j])   * exp2f(lbi0[j] - lbt0[j]));
        qd[kst].s[4+j] = f2bf(bf2f(qr.s[4+j]) * exp2f(lbi1[j] - lbt1[j]));
      }
    }
    #pragma unroll
    for (int nf = 0; nf < 4; ++nf) {
      FB s0f, s1f;
      s0f.u = *(const uint4*)&Swt[(nf*16+lr)*72 + ks];
      s1f.u = *(const uint4*)&Swt[(nf*16+lr)*72 + 32 + ks];
      acc[nf] = __builtin_amdgcn_mfma_f32_16x16x32_bf16(qd[0].h, s0f.h, acc[nf], 0,0,0);
      acc[nf] = __builtin_amdgcn_mfma_f32_16x16x32_bf16(qd[1].h, s1f.h, acc[nf], 0,0,0);
    }
    const int nb_ = (w & 1) ? 2 : 1;
    f32x4 dgc[2] = {{0.f,0.f,0.f,0.f},{0.f,0.f,0.f,0.f}};
    #pragma unroll
    for (int bf_ = 0; bf_ < 2; ++bf_) {
      if (bf_ < nb_) {
        int s = T + bf_*16 + lr;
        f32x4 z = {0.f,0.f,0.f,0.f};
        #pragma unroll
        for (int kst = 0; kst < 2; ++kst) {
          int ds = kst*32 + ks;
          f32x4 lbt0 = *(const f32x4*)&lb[T*68 + ds];
          f32x4 lbt1 = *(const f32x4*)&lb[T*68 + ds + 4];
          f32x4 lbs0 = *(const f32x4*)&lb[(s+1)*68 + ds];
          f32x4 lbs1 = *(const f32x4*)&lb[(s+1)*68 + ds + 4];
          FB kr, kd;
          kr.u = *(const uint4*)(kbuf + (rowbase + s)*DIMN + colbase + ds);
          #pragma unroll
          for (int j = 0; j < 4; ++j) {
            kd.s[j]   = f2bf(bf2f(kr.s[j])   * exp2f(lbt0[j] - lbs0[j]));
            kd.s[4+j] = f2bf(bf2f(kr.s[4+j]) * exp2f(lbt1[j] - lbs1[j]));
          }
          z = __builtin_amdgcn_mfma_f32_16x16x32_bf16(qd[kst].h, kd.h, z, 0,0,0);
        }
        dgc[bf_] = z;
      }
    }
    int iis = (w & 1)*16 + lg*4;
    #pragma unroll
    for (int bf_ = 0; bf_ < 2; ++bf_) {
      #pragma unroll
      for (int rg = 0; rg < 4; ++rg) {
        int ssu = bf_*16 + lr;
        float v = (bf_ < nb_ && ssu < iis + rg) ? dgc[bf_][rg] : 0.f;
        dgs[w*640 + (lg*4 + rg)*40 + bf_*16 + lr] = f2bf(v);
      }
    }
    FB dga;
    dga.u = *(const uint4*)&dgs[w*640 + lr*40 + ks];
    #pragma unroll
    for (int nf = 0; nf < 4; ++nf) {
      FB vv;
      vv.u = *(const uint4*)&vT[(nf*16+lr)*72 + T + ks];
      acc[nf] = __builtin_amdgcn_mfma_f32_16x16x32_bf16(dga.h, vv.h, acc[nf], 0,0,0);
    }
  };

  if (w < 2) do_inter(0);              // uses S0 (pre-commit)
  __syncthreads();
  {                                    // commit S1 in place
    int d0 = w*16 + lg*4;
    #pragma unroll
    for (int nf = 0; nf < 4; ++nf)
      *(u16x4*)&Swt[(nf*16+lr)*72 + d0] = s1v[nf];
  }
  __syncthreads();
  if (w >= 2) do_inter(32);            // uses S1 (post-commit)

  // ---- store ----
  #pragma unroll
  for (int nf = 0; nf < 4; ++nf)
    #pragma unroll
    for (int rg = 0; rg < 4; ++rg)
      outp[(rowbase + w*16 + lg*4 + rg)*DIMN + colbase + nf*16 + lr] = acc[nf][rg];
}

extern "C" void kernel_launch(void* const* d_in, const int* in_sizes, int n_in,
                              void* d_out, int out_size, void* d_ws, size_t ws_size,
                              hipStream_t stream) {
  const float* x   = (const float*)d_in[0];
  const float* Wq  = (const float*)d_in[1];
  const float* bq  = (const float*)d_in[2];
  const float* Wk  = (const float*)d_in[3];
  const float* bk  = (const float*)d_in[4];
  const float* Wv  = (const float*)d_in[5];
  const float* bv  = (const float*)d_in[6];
  const float* Wg1 = (const float*)d_in[7];
  const float* bg1 = (const float*)d_in[8];
  const float* Wg2 = (const float*)d_in[9];
  const float* bg2 = (const float*)d_in[10];
  float* out = (float*)d_out;

  float* ws = (float*)d_ws;
  const size_t NT = (size_t)NTOK*DIMN;  // 4194304
  const size_t NST = (size_t)NB*NH*NCHUNK*HD*HD;         // 4194304
  float* hid = ws;                                       // 65536 f32
  float* Bv  = hid + (size_t)NTOK*GH;                    // 65536 f32
  unsigned short* stb = (unsigned short*)(Bv + (size_t)NB*NH*NCHUNK*HD); // bf16 G->states
  unsigned short* xb = stb + NST;
  unsigned short* wt = xb + NT;                          // [3072][1024] bf16
  unsigned short* wg1b = wt + 3*(size_t)DIMN*DIMN;       // 16x1024 bf16
  unsigned short* qb = wg1b + (size_t)GH*DIMN;           // bf16 q/k/v
  unsigned short* kb = qb + NT;
  unsigned short* vb = kb + NT;

  k_cast_wT<<<dim3(16, 16, 3), 256, 0, stream>>>(Wq, Wk, Wv, wt);
  k_wg1t<<<(GH*DIMN)/256, 256, 0, stream>>>(Wg1, wg1b);
  k_castx_hidden<<<NTOK/16, 256, 0, stream>>>(x, wg1b, bg1, xb, hid);
  k_projqkv<<<dim3(24, 32), 256, 0, stream>>>(
      xb, wt, bq, bk, bv, qb, kb, vb);
  k_ginc<<<NB*NH*NCHUNK, 256, 0, stream>>>(kb, vb, hid, Wg2, bg2, stb, Bv);
  k_scan<<<(NB*NH*HD*HD)/256, 256, 0, stream>>>(stb, Bv);
  k_chunk<<<NB*NH*NCHUNK, 256, 0, stream>>>(qb, kb, vb, hid, Wg2, bg2, stb, out);
}

// Round 13
// 94.657 us; speedup vs baseline: 1.0211x; 1.0211x over previous
//
#include <hip/hip_runtime.h>
#include <math.h>

#define DIMN 1024
#define NH 16
#define HD 64
#define CHK 64
#define NB 2
#define SEQ 2048
#define NTOK (NB*SEQ)        // 4096
#define NCHUNK (SEQ/CHK)     // 32
#define GH 16

typedef __bf16 bf16x8 __attribute__((ext_vector_type(8)));
typedef float f32x4 __attribute__((ext_vector_type(4)));
typedef unsigned short u16x4 __attribute__((ext_vector_type(4)));

__device__ __forceinline__ unsigned short f2bf(float f) {
  union { float f; unsigned u; } a; a.f = f;
  unsigned r = a.u + 0x7FFFu + ((a.u >> 16) & 1u);
  return (unsigned short)(r >> 16);
}
__device__ __forceinline__ float bf2f(unsigned short v) {
  union { unsigned u; float f; } a; a.u = ((unsigned)v) << 16;
  return a.f;
}

__device__ __forceinline__ void gload16(const void* g, void* l) {
  __builtin_amdgcn_global_load_lds(
      (const __attribute__((address_space(1))) void*)g,
      (__attribute__((address_space(3))) void*)l, 16, 0, 0);
}

// ---- cast + transpose W (K x N f32) -> Wt (N x K bf16), LDS-tiled 64x64 ----
__global__ __launch_bounds__(256) void k_cast_wT(const float* __restrict__ W0,
    const float* __restrict__ W1, const float* __restrict__ W2,
    unsigned short* __restrict__ wt) {
  __shared__ float tile[64][68];
  int z = blockIdx.z;
  const float* W = z==0 ? W0 : z==1 ? W1 : W2;
  unsigned short* o = wt + (size_t)z*DIMN*DIMN;
  int k0 = blockIdx.y*64, n0 = blockIdx.x*64;
  int tr = threadIdx.x >> 4, c0 = (threadIdx.x & 15)*4;
  #pragma unroll
  for (int s = 0; s < 4; ++s) {
    int r = tr + s*16;
    *(f32x4*)&tile[r][c0] = *(const f32x4*)(W + (size_t)(k0+r)*DIMN + n0 + c0);
  }
  __syncthreads();
  #pragma unroll
  for (int s = 0; s < 4; ++s) {
    int nn = tr + s*16;
    ushort4 v;
    v.x = f2bf(tile[c0+0][nn]);
    v.y = f2bf(tile[c0+1][nn]);
    v.z = f2bf(tile[c0+2][nn]);
    v.w = f2bf(tile[c0+3][nn]);
    *(ushort4*)(o + (size_t)(n0+nn)*DIMN + k0 + c0) = v;
  }
}

// ---------------- transpose+cast Wg1 (1024x16 f32) -> wg1b (16x1024 bf16) ---
__global__ __launch_bounds__(256) void k_wg1t(const float* __restrict__ Wg1,
    unsigned short* __restrict__ wg1b) {
  int idx = blockIdx.x*256 + threadIdx.x;     // 16384
  int k = idx & 1023, j = idx >> 10;
  wg1b[j*DIMN + k] = f2bf(Wg1[k*GH + j]);
}

// ---- fused: cast x->bf16 (16-row tile via LDS) + hid = silu(xb@wg1b^T+bg1) --
__global__ __launch_bounds__(256) void k_castx_hidden(const float* __restrict__ x,
    const unsigned short* __restrict__ wg1b, const float* __restrict__ bg1,
    unsigned short* __restrict__ xb, float* __restrict__ hid) {
  __shared__ __align__(16) unsigned short xs[16][1032];  // pad: 2-way bank alias (free)
  __shared__ float red[4][16][16];
  int tid = threadIdx.x;
  size_t base = (size_t)blockIdx.x * 16 * DIMN;
  #pragma unroll
  for (int i = 0; i < 16; ++i) {
    int idx4 = tid + i*256;            // f32x4 index in tile, 0..4095
    int r = idx4 >> 8, c4 = idx4 & 255;
    f32x4 v = *(const f32x4*)(x + base + (size_t)idx4*4);
    u16x4 o;
    o[0]=f2bf(v[0]); o[1]=f2bf(v[1]); o[2]=f2bf(v[2]); o[3]=f2bf(v[3]);
    *(u16x4*)&xs[r][c4*4] = o;
    *(u16x4*)(xb + base + (size_t)idx4*4) = o;
  }
  __syncthreads();
  int l = tid & 63, w = tid >> 6;
  int lr = l & 15, kg = l >> 4;
  union FB { uint4 u; bf16x8 h; } a, b;
  f32x4 acc = {0.f,0.f,0.f,0.f};
  const unsigned short* wrow = wg1b + (size_t)lr*DIMN + w*256 + kg*8;
  #pragma unroll
  for (int kk = 0; kk < 8; ++kk) {
    a.u = *(const uint4*)&xs[lr][w*256 + kk*32 + kg*8];
    b.u = *(const uint4*)(wrow + kk*32);
    acc = __builtin_amdgcn_mfma_f32_16x16x32_bf16(a.h, b.h, acc, 0, 0, 0);
  }
  #pragma unroll
  for (int rg = 0; rg < 4; ++rg) red[w][kg*4 + rg][lr] = acc[rg];
  __syncthreads();
  {
    int m = tid >> 4, j = tid & 15;
    float s = red[0][m][j] + red[1][m][j] + red[2][m][j] + red[3][m][j];
    s += bg1[j];
    hid[(blockIdx.x*16 + m)*GH + j] = s / (1.f + expf(-s));   // silu
  }
}

// ---------------- fused bf16 MFMA projection: {q,k,v} = x @ [Wq|Wk|Wv] + b --
__global__ __launch_bounds__(256, 3) void k_projqkv(const unsigned short* __restrict__ xb,
    const unsigned short* __restrict__ wt,
    const float* __restrict__ b0, const float* __restrict__ b1, const float* __restrict__ b2,
    unsigned short* __restrict__ o0, unsigned short* __restrict__ o1,
    unsigned short* __restrict__ o2) {
  __shared__ unsigned short As[2][128*32];
  __shared__ unsigned short Bs[2][128*32];
  int tid = threadIdx.x;
  int wg = blockIdx.y * gridDim.x + blockIdx.x;   // 0..767 (768 % 8 == 0)
  int swz = (wg & 7) * 96 + (wg >> 3);
  int bx = swz % 24, by = swz / 24;
  int n3 = bx*128;
  int z = n3 >> 10;
  int n0l = n3 & 1023;
  const float* bias = z==0 ? b0 : z==1 ? b1 : b2;
  unsigned short* out = z==0 ? o0 : z==1 ? o1 : o2;
  int m0 = by*128;

  int l = tid & 63;
  int w = tid >> 6;
  int wr = w >> 1, wc = w & 1;
  int lrow = l & 15, kg = l >> 4;

  f32x4 acc[4][4] = {};

  int r0s = tid >> 2, s0s = tid & 3;
  int r1s = (tid + 256) >> 2;
  int sg0 = s0s ^ ((r0s >> 1) & 3);
  int sg1 = s0s ^ ((r1s >> 1) & 3);

  #define STAGE(buf, kt) do { \
    int kb_ = (kt)*32; \
    gload16(xb + ((size_t)(m0 + r0s)*DIMN + kb_ + sg0*8), &As[buf][tid*8]); \
    gload16(wt + ((size_t)(n3 + r0s)*DIMN + kb_ + sg0*8), &Bs[buf][tid*8]); \
    gload16(xb + ((size_t)(m0 + r1s)*DIMN + kb_ + sg1*8), &As[buf][(tid+256)*8]); \
    gload16(wt + ((size_t)(n3 + r1s)*DIMN + kb_ + sg1*8), &Bs[buf][(tid+256)*8]); \
  } while (0)

  STAGE(0, 0);
  int buf = 0;
  for (int t = 0; t < DIMN/32; ++t) {
    __syncthreads();
    if (t+1 < DIMN/32) STAGE(buf^1, t+1);
    union { uint4 u; bf16x8 h; } af[4], bfr[4];
    #pragma unroll
    for (int mf = 0; mf < 4; ++mf) {
      int r = wr*64 + mf*16 + lrow;
      int slot = kg ^ ((r >> 1) & 3);
      af[mf].u = *(const uint4*)&As[buf][r*32 + slot*8];
    }
    #pragma unroll
    for (int nf = 0; nf < 4; ++nf) {
      int r = wc*64 + nf*16 + lrow;
      int slot = kg ^ ((r >> 1) & 3);
      bfr[nf].u = *(const uint4*)&Bs[buf][r*32 + slot*8];
    }
    #pragma unroll
    for (int mf = 0; mf < 4; ++mf)
      #pragma unroll
      for (int nf = 0; nf < 4; ++nf)
        acc[mf][nf] = __builtin_amdgcn_mfma_f32_16x16x32_bf16(
            af[mf].h, bfr[nf].h, acc[mf][nf], 0, 0, 0);
    buf ^= 1;
  }
  #undef STAGE

  float bv[4];
  #pragma unroll
  for (int nf = 0; nf < 4; ++nf) bv[nf] = bias[n0l + wc*64 + nf*16 + lrow];
  #pragma unroll
  for (int mf = 0; mf < 4; ++mf) {
    int rbase = m0 + wr*64 + mf*16 + kg*4;
    #pragma unroll
    for (int nf = 0; nf < 4; ++nf) {
      int c = n0l + wc*64 + nf*16 + lrow;
      #pragma unroll
      for (int rg = 0; rg < 4; ++rg)
        out[(size_t)(rbase+rg)*DIMN + c] = f2bf(acc[mf][nf][rg] + bv[nf]);
    }
  }
}

// ---------------- pass 1a: per-chunk increment G_n via MFMA -----------------
// (256,4): 37KB LDS allows 4 blocks/CU -> 1024 blocks in one dispatch round.
__global__ __launch_bounds__(256, 4) void k_ginc(const unsigned short* __restrict__ kbuf,
    const unsigned short* __restrict__ vbuf,
    const float* __restrict__ hid, const float* __restrict__ Wg2,
    const float* __restrict__ bg2,
    unsigned short* __restrict__ G, float* __restrict__ Bv) {
  __shared__ __align__(16) unsigned short kb16[64*72];   // [i][d]
  __shared__ __align__(16) unsigned short vT[64*72];     // [e][i]
  __shared__ __align__(16) unsigned short kdT[64*72];    // [d][i]
  __shared__ __align__(16) float scr[2048];              // hid tile | Wg2 slice
  __shared__ float seg[4][64];
  int tid = threadIdx.x;
  int bid = blockIdx.x;                 // bh*NCHUNK + n
  int bh = bid >> 5, n = bid & 31;
  int b = bh >> 4, h = bh & 15;
  int colbase = h*HD;
  size_t rowbase = (size_t)b*SEQ + n*CHK;

  {
    int r = tid >> 2, j0 = (tid & 3)*4;
    *(f32x4*)&scr[r*16 + j0] = *(const f32x4*)(hid + (rowbase + r)*GH + j0);
    int j = tid >> 4, d0 = (tid & 15)*4;
    *(f32x4*)&scr[1024 + j*64 + d0] = *(const f32x4*)(Wg2 + (size_t)j*DIMN + colbase + d0);
  }
  #pragma unroll
  for (int i = 0; i < 4; ++i) {
    int f4 = tid + i*256;
    int r = f4 >> 4, cg = f4 & 15, c0 = cg*4;
    size_t g = (rowbase + r)*DIMN + colbase + c0;
    u16x4 k4 = *(const u16x4*)(kbuf + g);
    u16x4 v4 = *(const u16x4*)(vbuf + g);
    *(u16x4*)&kb16[r*72 + c0] = k4;
    #pragma unroll
    for (int j = 0; j < 4; ++j) vT[(c0+j)*72 + r] = v4[j];
  }
  __syncthreads();

  {
    int d = tid & 63, ig = tid >> 6;
    float wcol[16];
    #pragma unroll
    for (int j = 0; j < 16; ++j) wcol[j] = scr[1024 + j*64 + d];
    float bgd = bg2[colbase + d];
    float P[16];
    float run = 0.f;
    #pragma unroll
    for (int t = 0; t < 16; ++t) {
      int i = ig*16 + t;
      float acc = bgd;
      #pragma unroll
      for (int j = 0; j < 16; ++j) acc = fmaf(scr[i*16 + j], wcol[j], acc);
      float gg = 1.f/(1.f + expf(-acc));
      run += log2f(fmaf(0.9f, gg, 0.1f));
      P[t] = run;
    }
    seg[ig][d] = run;
    __syncthreads();
    float s0 = seg[0][d], s1 = seg[1][d], s2 = seg[2][d], s3 = seg[3][d];
    float carry = (ig > 0 ? s0 : 0.f) + (ig > 1 ? s1 : 0.f) + (ig > 2 ? s2 : 0.f);
    float Lb63 = s0 + s1 + s2 + s3;
    if (ig == 0) Bv[(size_t)bid*HD + d] = exp2f(Lb63);
    union { unsigned short s[16]; uint4 u[2]; } kd;
    #pragma unroll
    for (int t = 0; t < 16; ++t) {
      int i = ig*16 + t;
      float kv = bf2f(kb16[i*72 + d]);
      kd.s[t] = f2bf(kv * exp2f(Lb63 - carry - P[t]));   // suffix decay
    }
    *(uint4*)&kdT[d*72 + ig*16] = kd.u[0];
    *(uint4*)&kdT[d*72 + ig*16 + 8] = kd.u[1];
  }
  __syncthreads();

  int l = tid & 63, w = tid >> 6;
  int lr = l & 15, kg = l >> 4;
  int ks = kg*8;
  int arow = w*16 + lr;
  union FB { uint4 u; bf16x8 h; } a0, a1;
  a0.u = *(const uint4*)&kdT[arow*72 + ks];
  a1.u = *(const uint4*)&kdT[arow*72 + 32 + ks];
  unsigned short* gp = G + (size_t)bid*(HD*HD);
  #pragma unroll
  for (int nf = 0; nf < 4; ++nf) {
    FB b0v, b1v;
    b0v.u = *(const uint4*)&vT[(nf*16+lr)*72 + ks];
    b1v.u = *(const uint4*)&vT[(nf*16+lr)*72 + 32 + ks];
    f32x4 z = {0.f,0.f,0.f,0.f};
    z = __builtin_amdgcn_mfma_f32_16x16x32_bf16(a0.h, b0v.h, z, 0,0,0);
    z = __builtin_amdgcn_mfma_f32_16x16x32_bf16(a1.h, b1v.h, z, 0,0,0);
    #pragma unroll
    for (int rg = 0; rg < 4; ++rg)
      gp[(w*16 + kg*4 + rg)*HD + nf*16 + lr] = f2bf(z[rg]);
  }
}

// ---- pass 1b (parallel scan): preload-all then in-place bf16 G -> states ---
__global__ __launch_bounds__(256) void k_scan(unsigned short* __restrict__ buf,
    const float* __restrict__ Bv) {
  int idx = blockIdx.x*256 + threadIdx.x;   // 131072 = 32*64*64
  int e = idx & 63, d = (idx >> 6) & 63, bh = idx >> 12;
  unsigned short* gp = buf + (size_t)bh*NCHUNK*HD*HD + d*HD + e;
  const float* bp = Bv + (size_t)bh*NCHUNK*HD + d;
  float g[NCHUNK], bb[NCHUNK];
  #pragma unroll
  for (int n = 0; n < NCHUNK; ++n) g[n] = bf2f(gp[n*(HD*HD)]);
  #pragma unroll
  for (int n = 0; n < NCHUNK; ++n) bb[n] = bp[n*HD];
  float s = 0.f;
  #pragma unroll
  for (int n = 0; n < NCHUNK; ++n) {
    gp[n*(HD*HD)] = f2bf(s);
    s = fmaf(bb[n], s, g[n]);
  }
}

// ---------------- pass 2: MFMA per-chunk intra softmax + inter (sub=32) -----
// (R11 version: all operands LDS-resident; 2 blocks/CU)
__global__ __launch_bounds__(256) void k_chunk(const unsigned short* __restrict__ qbuf,
    const unsigned short* __restrict__ kbuf, const unsigned short* __restrict__ vbuf,
    const float* __restrict__ hid, const float* __restrict__ Wg2,
    const float* __restrict__ bg2,
    const unsigned short* __restrict__ states, float* __restrict__ outp) {
  __shared__ __align__(16) unsigned short qb16[64*72];
  __shared__ __align__(16) unsigned short kb16[64*72];
  __shared__ __align__(16) unsigned short vT[64*72];     // [e][s]
  __shared__ __align__(16) unsigned short Pl[64*72];     // [i][s]; early: f32 scratch
  __shared__ __align__(16) unsigned short Swt[2][64*72]; // [e][d] states (T=0, T=32)
  __shared__ __align__(16) float lb[65*68];              // [i][d] excl prefix log2(alpha)
  __shared__ __align__(16) unsigned short dgs[4][16*40]; // per-wave dg A staging
  __shared__ float seg[4][64];

  const int tid = threadIdx.x;
  const int bid = blockIdx.x;
  const int bh = bid >> 5, n = bid & 31;
  const int b = bh >> 4, h = bh & 15;
  const int colbase = h*HD;
  const size_t rowbase = (size_t)b*SEQ + n*CHK;
  const unsigned short* stp = states + (size_t)(bh*NCHUNK + n)*(HD*HD);

  float* scr = (float*)Pl;   // [0..1023]=hid, [1024..2047]=Wg2
  {
    int r = tid >> 2, j0 = (tid & 3)*4;
    *(f32x4*)&scr[r*16 + j0] = *(const f32x4*)(hid + (rowbase + r)*GH + j0);
    int j = tid >> 4, d0 = (tid & 15)*4;
    *(f32x4*)&scr[1024 + j*64 + d0] = *(const f32x4*)(Wg2 + (size_t)j*DIMN + colbase + d0);
  }
  #pragma unroll
  for (int i = 0; i < 4; ++i) {
    int f4 = tid + i*256;
    int r = f4 >> 4, cg = f4 & 15, c0 = cg*4;
    size_t g = (rowbase + r)*DIMN + colbase + c0;
    u16x4 q4 = *(const u16x4*)(qbuf + g);
    u16x4 k4 = *(const u16x4*)(kbuf + g);
    u16x4 v4 = *(const u16x4*)(vbuf + g);
    u16x4 s4 = *(const u16x4*)(stp + r*HD + c0);
    #pragma unroll
    for (int j = 0; j < 4; ++j) {
      vT[(c0+j)*72 + r] = v4[j];
      Swt[0][(c0+j)*72 + r] = s4[j];
    }
    *(u16x4*)&qb16[r*72 + c0] = q4;
    *(u16x4*)&kb16[r*72 + c0] = k4;
  }
  __syncthreads();

  {
    int r = tid >> 2, db = (tid & 3)*16;
    float av[16];
    #pragma unroll
    for (int dq = 0; dq < 16; ++dq) {
      int d = db + dq;
      float acc = bg2[colbase + d];
      #pragma unroll
      for (int j = 0; j < GH; ++j)
        acc = fmaf(scr[r*16 + j], scr[1024 + j*64 + d], acc);
      float gg = 1.f/(1.f + expf(-acc));
      av[dq] = log2f(fmaf(0.9f, gg, 0.1f));
    }
    #pragma unroll
    for (int dq = 0; dq < 16; dq += 4) {
      f32x4 v4 = {av[dq], av[dq+1], av[dq+2], av[dq+3]};
      *(f32x4*)&lb[r*68 + db + dq] = v4;
    }
  }
  __syncthreads();

  {
    int d = tid & 63, ww = tid >> 6;
    float run = 0.f;
    #pragma unroll
    for (int ii = 0; ii < 16; ++ii) {
      int i = ww*16 + ii;
      float t = lb[i*68 + d];
      lb[i*68 + d] = run;
      run += t;
    }
    seg[ww][d] = run;
  }
  __syncthreads();
  {
    int d = tid & 63, ww = tid >> 6;
    float carry = 0.f;
    for (int w2 = 0; w2 < ww; ++w2) carry += seg[w2][d];
    if (ww > 0)
      for (int ii = 0; ii < 16; ++ii) lb[(ww*16+ii)*68 + d] += carry;
    if (ww == 3) lb[64*68 + d] = carry + seg[3][d];
  }
  __syncthreads();

  const int l = tid & 63, w = tid >> 6;
  const int lr = l & 15, lg = l >> 4;
  const int ks = lg*8;
  const int arow = w*16 + lr;

  union FB { uint4 u; bf16x8 h; unsigned short s[8]; };

  // ---- QK^T (MFMA) ----
  FB qa0, qa1;
  qa0.u = *(const uint4*)&qb16[arow*72 + ks];
  qa1.u = *(const uint4*)&qb16[arow*72 + 32 + ks];
  f32x4 sc[4];
  #pragma unroll
  for (int nf = 0; nf < 4; ++nf) {
    FB b0, b1;
    b0.u = *(const uint4*)&kb16[(nf*16+lr)*72 + ks];
    b1.u = *(const uint4*)&kb16[(nf*16+lr)*72 + 32 + ks];
    f32x4 z = {0.f,0.f,0.f,0.f};
    z = __builtin_amdgcn_mfma_f32_16x16x32_bf16(qa0.h, b0.h, z, 0,0,0);
    z = __builtin_amdgcn_mfma_f32_16x16x32_bf16(qa1.h, b1.h, z, 0,0,0);
    sc[nf] = z;
  }

  // ---- in-register causal softmax ----
  float rmax[4] = {-3e38f,-3e38f,-3e38f,-3e38f};
  #pragma unroll
  for (int nf = 0; nf < 4; ++nf) {
    int col = nf*16 + lr;
    #pragma unroll
    for (int rg = 0; rg < 4; ++rg) {
      int row = w*16 + lg*4 + rg;
      float v = sc[nf][rg]*0.125f;
      if (col > row) v = -1e30f;
      sc[nf][rg] = v;
      rmax[rg] = fmaxf(rmax[rg], v);
    }
  }
  #pragma unroll
  for (int m = 1; m <= 8; m <<= 1)
    #pragma unroll
    for (int rg = 0; rg < 4; ++rg)
      rmax[rg] = fmaxf(rmax[rg], __shfl_xor(rmax[rg], m));
  float rsum[4] = {0.f,0.f,0.f,0.f};
  #pragma unroll
  for (int nf = 0; nf < 4; ++nf)
    #pragma unroll
    for (int rg = 0; rg < 4; ++rg) {
      float e = exp2f((sc[nf][rg] - rmax[rg])*1.44269504f);
      sc[nf][rg] = e;
      rsum[rg] += e;
    }
  #pragma unroll
  for (int m = 1; m <= 8; m <<= 1)
    #pragma unroll
    for (int rg = 0; rg < 4; ++rg)
      rsum[rg] += __shfl_xor(rsum[rg], m);
  __syncthreads();          // scr (Pl) reads done; safe to overwrite Pl
  #pragma unroll
  for (int nf = 0; nf < 4; ++nf)
    #pragma unroll
    for (int rg = 0; rg < 4; ++rg)
      Pl[(w*16 + lg*4 + rg)*72 + nf*16 + lr] = f2bf(sc[nf][rg]);
  float inv[4];
  #pragma unroll
  for (int rg = 0; rg < 4; ++rg) inv[rg] = 1.f/rsum[rg];
  __syncthreads();

  // ---- intra = P@V / rowsum (MFMA) ----
  f32x4 acc[4];
  {
    FB p0, p1;
    p0.u = *(const uint4*)&Pl[arow*72 + ks];
    p1.u = *(const uint4*)&Pl[arow*72 + 32 + ks];
    #pragma unroll
    for (int nf = 0; nf < 4; ++nf) {
      FB v0, v1;
      v0.u = *(const uint4*)&vT[(nf*16+lr)*72 + ks];
      v1.u = *(const uint4*)&vT[(nf*16+lr)*72 + 32 + ks];
      f32x4 z = {0.f,0.f,0.f,0.f};
      z = __builtin_amdgcn_mfma_f32_16x16x32_bf16(p0.h, v0.h, z, 0,0,0);
      z = __builtin_amdgcn_mfma_f32_16x16x32_bf16(p1.h, v1.h, z, 0,0,0);
      #pragma unroll
      for (int rg = 0; rg < 4; ++rg)
        acc[nf][rg] = z[rg]*inv[rg];
    }
  }

  // ---- state update: S1 = diag(exp2(lb32)) S0 + sum_{s<32} kupd_s v_s^T ----
  {
    int dA = arow;
    float lb32 = lb[32*68 + dA];
    FB ku;
    #pragma unroll
    for (int j = 0; j < 8; ++j) {
      int s = ks + j;
      float kv = bf2f(kb16[s*72 + dA]);
      ku.s[j] = f2bf(kv * exp2f(lb32 - lb[(s+1)*68 + dA]));
    }
    int d0 = w*16 + lg*4;
    float bs[4];
    #pragma unroll
    for (int rg = 0; rg < 4; ++rg) bs[rg] = exp2f(lb[32*68 + d0 + rg]);
    #pragma unroll
    for (int nf = 0; nf < 4; ++nf) {
      int e = nf*16 + lr;
      FB vv;
      vv.u = *(const uint4*)&vT[e*72 + ks];
      f32x4 z = {0.f,0.f,0.f,0.f};
      z = __builtin_amdgcn_mfma_f32_16x16x32_bf16(ku.h, vv.h, z, 0,0,0);
      u16x4 s0v = *(const u16x4*)&Swt[0][e*72 + d0];
      u16x4 s1v;
      #pragma unroll
      for (int rg = 0; rg < 4; ++rg)
        s1v[rg] = f2bf(z[rg] + bs[rg]*bf2f(s0v[rg]));
      *(u16x4*)&Swt[1][e*72 + d0] = s1v;
    }
  }
  __syncthreads();

  // ---- inter: cross (qdec @ S_T^T) + strict-lower diag, per wave ----
  {
    const int T = (w >= 2) ? 32 : 0;
    const unsigned short* Ssel = (w >= 2) ? &Swt[1][0] : &Swt[0][0];
    FB qd[2];
    #pragma unroll
    for (int kst = 0; kst < 2; ++kst) {
      int ds = kst*32 + ks;
      f32x4 lbi0 = *(const f32x4*)&lb[arow*68 + ds];
      f32x4 lbi1 = *(const f32x4*)&lb[arow*68 + ds + 4];
      f32x4 lbt0 = *(const f32x4*)&lb[T*68 + ds];
      f32x4 lbt1 = *(const f32x4*)&lb[T*68 + ds + 4];
      FB qr;
      qr.u = *(const uint4*)&qb16[arow*72 + ds];
      #pragma unroll
      for (int j = 0; j < 4; ++j) {
        qd[kst].s[j]   = f2bf(bf2f(qr.s[j])   * exp2f(lbi0[j] - lbt0[j]));
        qd[kst].s[4+j] = f2bf(bf2f(qr.s[4+j]) * exp2f(lbi1[j] - lbt1[j]));
      }
    }
    #pragma unroll
    for (int nf = 0; nf < 4; ++nf) {
      FB s0f, s1f;
      s0f.u = *(const uint4*)&Ssel[(nf*16+lr)*72 + ks];
      s1f.u = *(const uint4*)&Ssel[(nf*16+lr)*72 + 32 + ks];
      acc[nf] = __builtin_amdgcn_mfma_f32_16x16x32_bf16(qd[0].h, s0f.h, acc[nf], 0,0,0);
      acc[nf] = __builtin_amdgcn_mfma_f32_16x16x32_bf16(qd[1].h, s1f.h, acc[nf], 0,0,0);
    }
    const int nb_ = (w & 1) ? 2 : 1;
    f32x4 dgc[2] = {{0.f,0.f,0.f,0.f},{0.f,0.f,0.f,0.f}};
    #pragma unroll
    for (int bf_ = 0; bf_ < 2; ++bf_) {
      if (bf_ < nb_) {
        int s = T + bf_*16 + lr;
        f32x4 z = {0.f,0.f,0.f,0.f};
        #pragma unroll
        for (int kst = 0; kst < 2; ++kst) {
          int ds = kst*32 + ks;
          f32x4 lbt0 = *(const f32x4*)&lb[T*68 + ds];
          f32x4 lbt1 = *(const f32x4*)&lb[T*68 + ds + 4];
          f32x4 lbs0 = *(const f32x4*)&lb[(s+1)*68 + ds];
          f32x4 lbs1 = *(const f32x4*)&lb[(s+1)*68 + ds + 4];
          FB kr, kd;
          kr.u = *(const uint4*)&kb16[s*72 + ds];
          #pragma unroll
          for (int j = 0; j < 4; ++j) {
            kd.s[j]   = f2bf(bf2f(kr.s[j])   * exp2f(lbt0[j] - lbs0[j]));
            kd.s[4+j] = f2bf(bf2f(kr.s[4+j]) * exp2f(lbt1[j] - lbs1[j]));
          }
          z = __builtin_amdgcn_mfma_f32_16x16x32_bf16(qd[kst].h, kd.h, z, 0,0,0);
        }
        dgc[bf_] = z;
      }
    }
    int iis = (w & 1)*16 + lg*4;
    #pragma unroll
    for (int bf_ = 0; bf_ < 2; ++bf_) {
      #pragma unroll
      for (int rg = 0; rg < 4; ++rg) {
        int ssu = bf_*16 + lr;
        float v = (bf_ < nb_ && ssu < iis + rg) ? dgc[bf_][rg] : 0.f;
        dgs[w][(lg*4 + rg)*40 + bf_*16 + lr] = f2bf(v);
      }
    }
    FB dga;
    dga.u = *(const uint4*)&dgs[w][lr*40 + ks];
    #pragma unroll
    for (int nf = 0; nf < 4; ++nf) {
      FB vv;
      vv.u = *(const uint4*)&vT[(nf*16+lr)*72 + T + ks];
      acc[nf] = __builtin_amdgcn_mfma_f32_16x16x32_bf16(dga.h, vv.h, acc[nf], 0,0,0);
    }
  }

  // ---- store ----
  #pragma unroll
  for (int nf = 0; nf < 4; ++nf)
    #pragma unroll
    for (int rg = 0; rg < 4; ++rg)
      outp[(rowbase + w*16 + lg*4 + rg)*DIMN + colbase + nf*16 + lr] = acc[nf][rg];
}

extern "C" void kernel_launch(void* const* d_in, const int* in_sizes, int n_in,
                              void* d_out, int out_size, void* d_ws, size_t ws_size,
                              hipStream_t stream) {
  const float* x   = (const float*)d_in[0];
  const float* Wq  = (const float*)d_in[1];
  const float* bq  = (const float*)d_in[2];
  const float* Wk  = (const float*)d_in[3];
  const float* bk  = (const float*)d_in[4];
  const float* Wv  = (const float*)d_in[5];
  const float* bv  = (const float*)d_in[6];
  const float* Wg1 = (const float*)d_in[7];
  const float* bg1 = (const float*)d_in[8];
  const float* Wg2 = (const float*)d_in[9];
  const float* bg2 = (const float*)d_in[10];
  float* out = (float*)d_out;

  float* ws = (float*)d_ws;
  const size_t NT = (size_t)NTOK*DIMN;  // 4194304
  const size_t NST = (size_t)NB*NH*NCHUNK*HD*HD;         // 4194304
  float* hid = ws;                                       // 65536 f32
  float* Bv  = hid + (size_t)NTOK*GH;                    // 65536 f32
  unsigned short* stb = (unsigned short*)(Bv + (size_t)NB*NH*NCHUNK*HD); // bf16 G->states
  unsigned short* xb = stb + NST;
  unsigned short* wt = xb + NT;                          // [3072][1024] bf16
  unsigned short* wg1b = wt + 3*(size_t)DIMN*DIMN;       // 16x1024 bf16
  unsigned short* qb = wg1b + (size_t)GH*DIMN;           // bf16 q/k/v
  unsigned short* kb = qb + NT;
  unsigned short* vb = kb + NT;

  k_cast_wT<<<dim3(16, 16, 3), 256, 0, stream>>>(Wq, Wk, Wv, wt);
  k_wg1t<<<(GH*DIMN)/256, 256, 0, stream>>>(Wg1, wg1b);
  k_castx_hidden<<<NTOK/16, 256, 0, stream>>>(x, wg1b, bg1, xb, hid);
  k_projqkv<<<dim3(24, 32), 256, 0, stream>>>(
      xb, wt, bq, bk, bv, qb, kb, vb);
  k_ginc<<<NB*NH*NCHUNK, 256, 0, stream>>>(kb, vb, hid, Wg2, bg2, stb, Bv);
  k_scan<<<(NB*NH*HD*HD)/256, 256, 0, stream>>>(stb, Bv);
  k_chunk<<<NB*NH*NCHUNK, 256, 0, stream>>>(qb, kb, vb, hid, Wg2, bg2, stb, out);
}

// Round 14
// 94.297 us; speedup vs baseline: 1.0250x; 1.0038x over previous
//
#include <hip/hip_runtime.h>
#include <math.h>

#define DIMN 1024
#define NH 16
#define HD 64
#define CHK 64
#define NB 2
#define SEQ 2048
#define NTOK (NB*SEQ)        // 4096
#define NCHUNK (SEQ/CHK)     // 32
#define GH 16

typedef __bf16 bf16x8 __attribute__((ext_vector_type(8)));
typedef float f32x4 __attribute__((ext_vector_type(4)));
typedef unsigned short u16x4 __attribute__((ext_vector_type(4)));

__device__ __forceinline__ unsigned short f2bf(float f) {
  union { float f; unsigned u; } a; a.f = f;
  unsigned r = a.u + 0x7FFFu + ((a.u >> 16) & 1u);
  return (unsigned short)(r >> 16);
}
__device__ __forceinline__ float bf2f(unsigned short v) {
  union { unsigned u; float f; } a; a.u = ((unsigned)v) << 16;
  return a.f;
}

__device__ __forceinline__ void gload16(const void* g, void* l) {
  __builtin_amdgcn_global_load_lds(
      (const __attribute__((address_space(1))) void*)g,
      (__attribute__((address_space(3))) void*)l, 16, 0, 0);
}

// ---- cast + transpose W (K x N f32) -> Wt (N x K bf16), LDS-tiled 64x64 ----
__global__ __launch_bounds__(256) void k_cast_wT(const float* __restrict__ W0,
    const float* __restrict__ W1, const float* __restrict__ W2,
    unsigned short* __restrict__ wt) {
  __shared__ float tile[64][68];
  int z = blockIdx.z;
  const float* W = z==0 ? W0 : z==1 ? W1 : W2;
  unsigned short* o = wt + (size_t)z*DIMN*DIMN;
  int k0 = blockIdx.y*64, n0 = blockIdx.x*64;
  int tr = threadIdx.x >> 4, c0 = (threadIdx.x & 15)*4;
  #pragma unroll
  for (int s = 0; s < 4; ++s) {
    int r = tr + s*16;
    *(f32x4*)&tile[r][c0] = *(const f32x4*)(W + (size_t)(k0+r)*DIMN + n0 + c0);
  }
  __syncthreads();
  #pragma unroll
  for (int s = 0; s < 4; ++s) {
    int nn = tr + s*16;
    ushort4 v;
    v.x = f2bf(tile[c0+0][nn]);
    v.y = f2bf(tile[c0+1][nn]);
    v.z = f2bf(tile[c0+2][nn]);
    v.w = f2bf(tile[c0+3][nn]);
    *(ushort4*)(o + (size_t)(n0+nn)*DIMN + k0 + c0) = v;
  }
}

// ---------------- transpose+cast Wg1 (1024x16 f32) -> wg1b (16x1024 bf16) ---
__global__ __launch_bounds__(256) void k_wg1t(const float* __restrict__ Wg1,
    unsigned short* __restrict__ wg1b) {
  int idx = blockIdx.x*256 + threadIdx.x;     // 16384
  int k = idx & 1023, j = idx >> 10;
  wg1b[j*DIMN + k] = f2bf(Wg1[k*GH + j]);
}

// ---- fused: cast x->bf16 (16-row tile via LDS) + hid = silu(xb@wg1b^T+bg1) --
__global__ __launch_bounds__(256) void k_castx_hidden(const float* __restrict__ x,
    const unsigned short* __restrict__ wg1b, const float* __restrict__ bg1,
    unsigned short* __restrict__ xb, float* __restrict__ hid) {
  __shared__ __align__(16) unsigned short xs[16][1032];  // pad: 2-way bank alias (free)
  __shared__ float red[4][16][16];
  int tid = threadIdx.x;
  size_t base = (size_t)blockIdx.x * 16 * DIMN;
  #pragma unroll
  for (int i = 0; i < 16; ++i) {
    int idx4 = tid + i*256;            // f32x4 index in tile, 0..4095
    int r = idx4 >> 8, c4 = idx4 & 255;
    f32x4 v = *(const f32x4*)(x + base + (size_t)idx4*4);
    u16x4 o;
    o[0]=f2bf(v[0]); o[1]=f2bf(v[1]); o[2]=f2bf(v[2]); o[3]=f2bf(v[3]);
    *(u16x4*)&xs[r][c4*4] = o;
    *(u16x4*)(xb + base + (size_t)idx4*4) = o;
  }
  __syncthreads();
  int l = tid & 63, w = tid >> 6;
  int lr = l & 15, kg = l >> 4;
  union FB { uint4 u; bf16x8 h; } a, b;
  f32x4 acc = {0.f,0.f,0.f,0.f};
  const unsigned short* wrow = wg1b + (size_t)lr*DIMN + w*256 + kg*8;
  #pragma unroll
  for (int kk = 0; kk < 8; ++kk) {
    a.u = *(const uint4*)&xs[lr][w*256 + kk*32 + kg*8];
    b.u = *(const uint4*)(wrow + kk*32);
    acc = __builtin_amdgcn_mfma_f32_16x16x32_bf16(a.h, b.h, acc, 0, 0, 0);
  }
  #pragma unroll
  for (int rg = 0; rg < 4; ++rg) red[w][kg*4 + rg][lr] = acc[rg];
  __syncthreads();
  {
    int m = tid >> 4, j = tid & 15;
    float s = red[0][m][j] + red[1][m][j] + red[2][m][j] + red[3][m][j];
    s += bg1[j];
    hid[(blockIdx.x*16 + m)*GH + j] = s / (1.f + expf(-s));   // silu
  }
}

// ---------------- fused bf16 MFMA projection: {q,k,v} = x @ [Wq|Wk|Wv] + b --
// 3-buffer LDS rotation, 2-deep prefetch, counted vmcnt + raw s_barrier (T4).
// Per iter: vmcnt(4) guarantees tile t resident (each wave confirms its own
// loads BEFORE the barrier); STAGE(t+2) writes the buffer last read at t-1.
__global__ __launch_bounds__(256, 3) void k_projqkv(const unsigned short* __restrict__ xb,
    const unsigned short* __restrict__ wt,
    const float* __restrict__ b0, const float* __restrict__ b1, const float* __restrict__ b2,
    unsigned short* __restrict__ o0, unsigned short* __restrict__ o1,
    unsigned short* __restrict__ o2) {
  __shared__ unsigned short As[3][128*32];
  __shared__ unsigned short Bs[3][128*32];
  int tid = threadIdx.x;
  int wg = blockIdx.y * gridDim.x + blockIdx.x;   // 0..767 (768 % 8 == 0)
  int swz = (wg & 7) * 96 + (wg >> 3);
  int bx = swz % 24, by = swz / 24;
  int n3 = bx*128;
  int z = n3 >> 10;
  int n0l = n3 & 1023;
  const float* bias = z==0 ? b0 : z==1 ? b1 : b2;
  unsigned short* out = z==0 ? o0 : z==1 ? o1 : o2;
  int m0 = by*128;

  int l = tid & 63;
  int w = tid >> 6;
  int wr = w >> 1, wc = w & 1;
  int lrow = l & 15, kg = l >> 4;

  f32x4 acc[4][4] = {};

  int r0s = tid >> 2, s0s = tid & 3;
  int r1s = (tid + 256) >> 2;
  int sg0 = s0s ^ ((r0s >> 1) & 3);
  int sg1 = s0s ^ ((r1s >> 1) & 3);

  #define STAGE(buf, kt) do { \
    int kb_ = (kt)*32; \
    gload16(xb + ((size_t)(m0 + r0s)*DIMN + kb_ + sg0*8), &As[buf][tid*8]); \
    gload16(wt + ((size_t)(n3 + r0s)*DIMN + kb_ + sg0*8), &Bs[buf][tid*8]); \
    gload16(xb + ((size_t)(m0 + r1s)*DIMN + kb_ + sg1*8), &As[buf][(tid+256)*8]); \
    gload16(wt + ((size_t)(n3 + r1s)*DIMN + kb_ + sg1*8), &Bs[buf][(tid+256)*8]); \
  } while (0)

  STAGE(0, 0);
  STAGE(1, 1);
  for (int t = 0; t < DIMN/32; ++t) {
    if (t < DIMN/32 - 1) {
      asm volatile("s_waitcnt vmcnt(4)" ::: "memory");   // tile t resident (own loads)
    } else {
      asm volatile("s_waitcnt vmcnt(0)" ::: "memory");   // final tile
    }
    __builtin_amdgcn_s_barrier();                        // all waves confirmed tile t
    if (t+2 < DIMN/32) STAGE((t+2)%3, t+2);              // overwrite buf read at t-1
    int buf = t % 3;
    union { uint4 u; bf16x8 h; } af[4], bfr[4];
    #pragma unroll
    for (int mf = 0; mf < 4; ++mf) {
      int r = wr*64 + mf*16 + lrow;
      int slot = kg ^ ((r >> 1) & 3);
      af[mf].u = *(const uint4*)&As[buf][r*32 + slot*8];
    }
    #pragma unroll
    for (int nf = 0; nf < 4; ++nf) {
      int r = wc*64 + nf*16 + lrow;
      int slot = kg ^ ((r >> 1) & 3);
      bfr[nf].u = *(const uint4*)&Bs[buf][r*32 + slot*8];
    }
    #pragma unroll
    for (int mf = 0; mf < 4; ++mf)
      #pragma unroll
      for (int nf = 0; nf < 4; ++nf)
        acc[mf][nf] = __builtin_amdgcn_mfma_f32_16x16x32_bf16(
            af[mf].h, bfr[nf].h, acc[mf][nf], 0, 0, 0);
  }
  #undef STAGE

  float bv[4];
  #pragma unroll
  for (int nf = 0; nf < 4; ++nf) bv[nf] = bias[n0l + wc*64 + nf*16 + lrow];
  #pragma unroll
  for (int mf = 0; mf < 4; ++mf) {
    int rbase = m0 + wr*64 + mf*16 + kg*4;
    #pragma unroll
    for (int nf = 0; nf < 4; ++nf) {
      int c = n0l + wc*64 + nf*16 + lrow;
      #pragma unroll
      for (int rg = 0; rg < 4; ++rg)
        out[(size_t)(rbase+rg)*DIMN + c] = f2bf(acc[mf][nf][rg] + bv[nf]);
    }
  }
}

// ---------------- pass 1a: per-chunk increment G_n via MFMA -----------------
__global__ __launch_bounds__(256, 4) void k_ginc(const unsigned short* __restrict__ kbuf,
    const unsigned short* __restrict__ vbuf,
    const float* __restrict__ hid, const float* __restrict__ Wg2,
    const float* __restrict__ bg2,
    unsigned short* __restrict__ G, float* __restrict__ Bv) {
  __shared__ __align__(16) unsigned short kb16[64*72];   // [i][d]
  __shared__ __align__(16) unsigned short vT[64*72];     // [e][i]
  __shared__ __align__(16) unsigned short kdT[64*72];    // [d][i]
  __shared__ __align__(16) float scr[2048];              // hid tile | Wg2 slice
  __shared__ float seg[4][64];
  int tid = threadIdx.x;
  int bid = blockIdx.x;                 // bh*NCHUNK + n
  int bh = bid >> 5, n = bid & 31;
  int b = bh >> 4, h = bh & 15;
  int colbase = h*HD;
  size_t rowbase = (size_t)b*SEQ + n*CHK;

  {
    int r = tid >> 2, j0 = (tid & 3)*4;
    *(f32x4*)&scr[r*16 + j0] = *(const f32x4*)(hid + (rowbase + r)*GH + j0);
    int j = tid >> 4, d0 = (tid & 15)*4;
    *(f32x4*)&scr[1024 + j*64 + d0] = *(const f32x4*)(Wg2 + (size_t)j*DIMN + colbase + d0);
  }
  #pragma unroll
  for (int i = 0; i < 4; ++i) {
    int f4 = tid + i*256;
    int r = f4 >> 4, cg = f4 & 15, c0 = cg*4;
    size_t g = (rowbase + r)*DIMN + colbase + c0;
    u16x4 k4 = *(const u16x4*)(kbuf + g);
    u16x4 v4 = *(const u16x4*)(vbuf + g);
    *(u16x4*)&kb16[r*72 + c0] = k4;
    #pragma unroll
    for (int j = 0; j < 4; ++j) vT[(c0+j)*72 + r] = v4[j];
  }
  __syncthreads();

  {
    int d = tid & 63, ig = tid >> 6;
    float wcol[16];
    #pragma unroll
    for (int j = 0; j < 16; ++j) wcol[j] = scr[1024 + j*64 + d];
    float bgd = bg2[colbase + d];
    float P[16];
    float run = 0.f;
    #pragma unroll
    for (int t = 0; t < 16; ++t) {
      int i = ig*16 + t;
      float acc = bgd;
      #pragma unroll
      for (int j = 0; j < 16; ++j) acc = fmaf(scr[i*16 + j], wcol[j], acc);
      float gg = 1.f/(1.f + expf(-acc));
      run += log2f(fmaf(0.9f, gg, 0.1f));
      P[t] = run;
    }
    seg[ig][d] = run;
    __syncthreads();
    float s0 = seg[0][d], s1 = seg[1][d], s2 = seg[2][d], s3 = seg[3][d];
    float carry = (ig > 0 ? s0 : 0.f) + (ig > 1 ? s1 : 0.f) + (ig > 2 ? s2 : 0.f);
    float Lb63 = s0 + s1 + s2 + s3;
    if (ig == 0) Bv[(size_t)bid*HD + d] = exp2f(Lb63);
    union { unsigned short s[16]; uint4 u[2]; } kd;
    #pragma unroll
    for (int t = 0; t < 16; ++t) {
      int i = ig*16 + t;
      float kv = bf2f(kb16[i*72 + d]);
      kd.s[t] = f2bf(kv * exp2f(Lb63 - carry - P[t]));   // suffix decay
    }
    *(uint4*)&kdT[d*72 + ig*16] = kd.u[0];
    *(uint4*)&kdT[d*72 + ig*16 + 8] = kd.u[1];
  }
  __syncthreads();

  int l = tid & 63, w = tid >> 6;
  int lr = l & 15, kg = l >> 4;
  int ks = kg*8;
  int arow = w*16 + lr;
  union FB { uint4 u; bf16x8 h; } a0, a1;
  a0.u = *(const uint4*)&kdT[arow*72 + ks];
  a1.u = *(const uint4*)&kdT[arow*72 + 32 + ks];
  unsigned short* gp = G + (size_t)bid*(HD*HD);
  #pragma unroll
  for (int nf = 0; nf < 4; ++nf) {
    FB b0v, b1v;
    b0v.u = *(const uint4*)&vT[(nf*16+lr)*72 + ks];
    b1v.u = *(const uint4*)&vT[(nf*16+lr)*72 + 32 + ks];
    f32x4 z = {0.f,0.f,0.f,0.f};
    z = __builtin_amdgcn_mfma_f32_16x16x32_bf16(a0.h, b0v.h, z, 0,0,0);
    z = __builtin_amdgcn_mfma_f32_16x16x32_bf16(a1.h, b1v.h, z, 0,0,0);
    #pragma unroll
    for (int rg = 0; rg < 4; ++rg)
      gp[(w*16 + kg*4 + rg)*HD + nf*16 + lr] = f2bf(z[rg]);
  }
}

// ---- pass 1b (parallel scan): preload-all then in-place bf16 G -> states ---
__global__ __launch_bounds__(256) void k_scan(unsigned short* __restrict__ buf,
    const float* __restrict__ Bv) {
  int idx = blockIdx.x*256 + threadIdx.x;   // 131072 = 32*64*64
  int e = idx & 63, d = (idx >> 6) & 63, bh = idx >> 12;
  unsigned short* gp = buf + (size_t)bh*NCHUNK*HD*HD + d*HD + e;
  const float* bp = Bv + (size_t)bh*NCHUNK*HD + d;
  float g[NCHUNK], bb[NCHUNK];
  #pragma unroll
  for (int n = 0; n < NCHUNK; ++n) g[n] = bf2f(gp[n*(HD*HD)]);
  #pragma unroll
  for (int n = 0; n < NCHUNK; ++n) bb[n] = bp[n*HD];
  float s = 0.f;
  #pragma unroll
  for (int n = 0; n < NCHUNK; ++n) {
    gp[n*(HD*HD)] = f2bf(s);
    s = fmaf(bb[n], s, g[n]);
  }
}

// ---------------- pass 2: MFMA per-chunk intra softmax + inter (sub=32) -----
__global__ __launch_bounds__(256) void k_chunk(const unsigned short* __restrict__ qbuf,
    const unsigned short* __restrict__ kbuf, const unsigned short* __restrict__ vbuf,
    const float* __restrict__ hid, const float* __restrict__ Wg2,
    const float* __restrict__ bg2,
    const unsigned short* __restrict__ states, float* __restrict__ outp) {
  __shared__ __align__(16) unsigned short qb16[64*72];
  __shared__ __align__(16) unsigned short kb16[64*72];
  __shared__ __align__(16) unsigned short vT[64*72];     // [e][s]
  __shared__ __align__(16) unsigned short Pl[64*72];     // [i][s]; early: f32 scratch
  __shared__ __align__(16) unsigned short Swt[2][64*72]; // [e][d] states (T=0, T=32)
  __shared__ __align__(16) float lb[65*68];              // [i][d] excl prefix log2(alpha)
  __shared__ __align__(16) unsigned short dgs[4][16*40]; // per-wave dg A staging
  __shared__ float seg[4][64];

  const int tid = threadIdx.x;
  const int bid = blockIdx.x;
  const int bh = bid >> 5, n = bid & 31;
  const int b = bh >> 4, h = bh & 15;
  const int colbase = h*HD;
  const size_t rowbase = (size_t)b*SEQ + n*CHK;
  const unsigned short* stp = states + (size_t)(bh*NCHUNK + n)*(HD*HD);

  float* scr = (float*)Pl;   // [0..1023]=hid, [1024..2047]=Wg2
  {
    int r = tid >> 2, j0 = (tid & 3)*4;
    *(f32x4*)&scr[r*16 + j0] = *(const f32x4*)(hid + (rowbase + r)*GH + j0);
    int j = tid >> 4, d0 = (tid & 15)*4;
    *(f32x4*)&scr[1024 + j*64 + d0] = *(const f32x4*)(Wg2 + (size_t)j*DIMN + colbase + d0);
  }
  #pragma unroll
  for (int i = 0; i < 4; ++i) {
    int f4 = tid + i*256;
    int r = f4 >> 4, cg = f4 & 15, c0 = cg*4;
    size_t g = (rowbase + r)*DIMN + colbase + c0;
    u16x4 q4 = *(const u16x4*)(qbuf + g);
    u16x4 k4 = *(const u16x4*)(kbuf + g);
    u16x4 v4 = *(const u16x4*)(vbuf + g);
    u16x4 s4 = *(const u16x4*)(stp + r*HD + c0);
    #pragma unroll
    for (int j = 0; j < 4; ++j) {
      vT[(c0+j)*72 + r] = v4[j];
      Swt[0][(c0+j)*72 + r] = s4[j];
    }
    *(u16x4*)&qb16[r*72 + c0] = q4;
    *(u16x4*)&kb16[r*72 + c0] = k4;
  }
  __syncthreads();

  {
    int r = tid >> 2, db = (tid & 3)*16;
    float av[16];
    #pragma unroll
    for (int dq = 0; dq < 16; ++dq) {
      int d = db + dq;
      float acc = bg2[colbase + d];
      #pragma unroll
      for (int j = 0; j < GH; ++j)
        acc = fmaf(scr[r*16 + j], scr[1024 + j*64 + d], acc);
      float gg = 1.f/(1.f + expf(-acc));
      av[dq] = log2f(fmaf(0.9f, gg, 0.1f));
    }
    #pragma unroll
    for (int dq = 0; dq < 16; dq += 4) {
      f32x4 v4 = {av[dq], av[dq+1], av[dq+2], av[dq+3]};
      *(f32x4*)&lb[r*68 + db + dq] = v4;
    }
  }
  __syncthreads();

  {
    int d = tid & 63, ww = tid >> 6;
    float run = 0.f;
    #pragma unroll
    for (int ii = 0; ii < 16; ++ii) {
      int i = ww*16 + ii;
      float t = lb[i*68 + d];
      lb[i*68 + d] = run;
      run += t;
    }
    seg[ww][d] = run;
  }
  __syncthreads();
  {
    int d = tid & 63, ww = tid >> 6;
    float carry = 0.f;
    for (int w2 = 0; w2 < ww; ++w2) carry += seg[w2][d];
    if (ww > 0)
      for (int ii = 0; ii < 16; ++ii) lb[(ww*16+ii)*68 + d] += carry;
    if (ww == 3) lb[64*68 + d] = carry + seg[3][d];
  }
  __syncthreads();

  const int l = tid & 63, w = tid >> 6;
  const int lr = l & 15, lg = l >> 4;
  const int ks = lg*8;
  const int arow = w*16 + lr;

  union FB { uint4 u; bf16x8 h; unsigned short s[8]; };

  // ---- QK^T (MFMA) ----
  FB qa0, qa1;
  qa0.u = *(const uint4*)&qb16[arow*72 + ks];
  qa1.u = *(const uint4*)&qb16[arow*72 + 32 + ks];
  f32x4 sc[4];
  #pragma unroll
  for (int nf = 0; nf < 4; ++nf) {
    FB b0, b1;
    b0.u = *(const uint4*)&kb16[(nf*16+lr)*72 + ks];
    b1.u = *(const uint4*)&kb16[(nf*16+lr)*72 + 32 + ks];
    f32x4 z = {0.f,0.f,0.f,0.f};
    z = __builtin_amdgcn_mfma_f32_16x16x32_bf16(qa0.h, b0.h, z, 0,0,0);
    z = __builtin_amdgcn_mfma_f32_16x16x32_bf16(qa1.h, b1.h, z, 0,0,0);
    sc[nf] = z;
  }

  // ---- in-register causal softmax ----
  float rmax[4] = {-3e38f,-3e38f,-3e38f,-3e38f};
  #pragma unroll
  for (int nf = 0; nf < 4; ++nf) {
    int col = nf*16 + lr;
    #pragma unroll
    for (int rg = 0; rg < 4; ++rg) {
      int row = w*16 + lg*4 + rg;
      float v = sc[nf][rg]*0.125f;
      if (col > row) v = -1e30f;
      sc[nf][rg] = v;
      rmax[rg] = fmaxf(rmax[rg], v);
    }
  }
  #pragma unroll
  for (int m = 1; m <= 8; m <<= 1)
    #pragma unroll
    for (int rg = 0; rg < 4; ++rg)
      rmax[rg] = fmaxf(rmax[rg], __shfl_xor(rmax[rg], m));
  float rsum[4] = {0.f,0.f,0.f,0.f};
  #pragma unroll
  for (int nf = 0; nf < 4; ++nf)
    #pragma unroll
    for (int rg = 0; rg < 4; ++rg) {
      float e = exp2f((sc[nf][rg] - rmax[rg])*1.44269504f);
      sc[nf][rg] = e;
      rsum[rg] += e;
    }
  #pragma unroll
  for (int m = 1; m <= 8; m <<= 1)
    #pragma unroll
    for (int rg = 0; rg < 4; ++rg)
      rsum[rg] += __shfl_xor(rsum[rg], m);
  __syncthreads();          // scr (Pl) reads done; safe to overwrite Pl
  #pragma unroll
  for (int nf = 0; nf < 4; ++nf)
    #pragma unroll
    for (int rg = 0; rg < 4; ++rg)
      Pl[(w*16 + lg*4 + rg)*72 + nf*16 + lr] = f2bf(sc[nf][rg]);
  float inv[4];
  #pragma unroll
  for (int rg = 0; rg < 4; ++rg) inv[rg] = 1.f/rsum[rg];
  __syncthreads();

  // ---- intra = P@V / rowsum (MFMA) ----
  f32x4 acc[4];
  {
    FB p0, p1;
    p0.u = *(const uint4*)&Pl[arow*72 + ks];
    p1.u = *(const uint4*)&Pl[arow*72 + 32 + ks];
    #pragma unroll
    for (int nf = 0; nf < 4; ++nf) {
      FB v0, v1;
      v0.u = *(const uint4*)&vT[(nf*16+lr)*72 + ks];
      v1.u = *(const uint4*)&vT[(nf*16+lr)*72 + 32 + ks];
      f32x4 z = {0.f,0.f,0.f,0.f};
      z = __builtin_amdgcn_mfma_f32_16x16x32_bf16(p0.h, v0.h, z, 0,0,0);
      z = __builtin_amdgcn_mfma_f32_16x16x32_bf16(p1.h, v1.h, z, 0,0,0);
      #pragma unroll
      for (int rg = 0; rg < 4; ++rg)
        acc[nf][rg] = z[rg]*inv[rg];
    }
  }

  // ---- state update: S1 = diag(exp2(lb32)) S0 + sum_{s<32} kupd_s v_s^T ----
  {
    int dA = arow;
    float lb32 = lb[32*68 + dA];
    FB ku;
    #pragma unroll
    for (int j = 0; j < 8; ++j) {
      int s = ks + j;
      float kv = bf2f(kb16[s*72 + dA]);
      ku.s[j] = f2bf(kv * exp2f(lb32 - lb[(s+1)*68 + dA]));
    }
    int d0 = w*16 + lg*4;
    float bs[4];
    #pragma unroll
    for (int rg = 0; rg < 4; ++rg) bs[rg] = exp2f(lb[32*68 + d0 + rg]);
    #pragma unroll
    for (int nf = 0; nf < 4; ++nf) {
      int e = nf*16 + lr;
      FB vv;
      vv.u = *(const uint4*)&vT[e*72 + ks];
      f32x4 z = {0.f,0.f,0.f,0.f};
      z = __builtin_amdgcn_mfma_f32_16x16x32_bf16(ku.h, vv.h, z, 0,0,0);
      u16x4 s0v = *(const u16x4*)&Swt[0][e*72 + d0];
      u16x4 s1v;
      #pragma unroll
      for (int rg = 0; rg < 4; ++rg)
        s1v[rg] = f2bf(z[rg] + bs[rg]*bf2f(s0v[rg]));
      *(u16x4*)&Swt[1][e*72 + d0] = s1v;
    }
  }
  __syncthreads();

  // ---- inter: cross (qdec @ S_T^T) + strict-lower diag, per wave ----
  {
    const int T = (w >= 2) ? 32 : 0;
    const unsigned short* Ssel = (w >= 2) ? &Swt[1][0] : &Swt[0][0];
    FB qd[2];
    #pragma unroll
    for (int kst = 0; kst < 2; ++kst) {
      int ds = kst*32 + ks;
      f32x4 lbi0 = *(const f32x4*)&lb[arow*68 + ds];
      f32x4 lbi1 = *(const f32x4*)&lb[arow*68 + ds + 4];
      f32x4 lbt0 = *(const f32x4*)&lb[T*68 + ds];
      f32x4 lbt1 = *(const f32x4*)&lb[T*68 + ds + 4];
      FB qr;
      qr.u = *(const uint4*)&qb16[arow*72 + ds];
      #pragma unroll
      for (int j = 0; j < 4; ++j) {
        qd[kst].s[j]   = f2bf(bf2f(qr.s[j])   * exp2f(lbi0[j] - lbt0[j]));
        qd[kst].s[4+j] = f2bf(bf2f(qr.s[4+j]) * exp2f(lbi1[j] - lbt1[j]));
      }
    }
    #pragma unroll
    for (int nf = 0; nf < 4; ++nf) {
      FB s0f, s1f;
      s0f.u = *(const uint4*)&Ssel[(nf*16+lr)*72 + ks];
      s1f.u = *(const uint4*)&Ssel[(nf*16+lr)*72 + 32 + ks];
      acc[nf] = __builtin_amdgcn_mfma_f32_16x16x32_bf16(qd[0].h, s0f.h, acc[nf], 0,0,0);
      acc[nf] = __builtin_amdgcn_mfma_f32_16x16x32_bf16(qd[1].h, s1f.h, acc[nf], 0,0,0);
    }
    const int nb_ = (w & 1) ? 2 : 1;
    f32x4 dgc[2] = {{0.f,0.f,0.f,0.f},{0.f,0.f,0.f,0.f}};
    #pragma unroll
    for (int bf_ = 0; bf_ < 2; ++bf_) {
      if (bf_ < nb_) {
        int s = T + bf_*16 + lr;
        f32x4 z = {0.f,0.f,0.f,0.f};
        #pragma unroll
        for (int kst = 0; kst < 2; ++kst) {
          int ds = kst*32 + ks;
          f32x4 lbt0 = *(const f32x4*)&lb[T*68 + ds];
          f32x4 lbt1 = *(const f32x4*)&lb[T*68 + ds + 4];
          f32x4 lbs0 = *(const f32x4*)&lb[(s+1)*68 + ds];
          f32x4 lbs1 = *(const f32x4*)&lb[(s+1)*68 + ds + 4];
          FB kr, kd;
          kr.u = *(const uint4*)&kb16[s*72 + ds];
          #pragma unroll
          for (int j = 0; j < 4; ++j) {
            kd.s[j]   = f2bf(bf2f(kr.s[j])   * exp2f(lbt0[j] - lbs0[j]));
            kd.s[4+j] = f2bf(bf2f(kr.s[4+j]) * exp2f(lbt1[j] - lbs1[j]));
          }
          z = __builtin_amdgcn_mfma_f32_16x16x32_bf16(qd[kst].h, kd.h, z, 0,0,0);
        }
        dgc[bf_] = z;
      }
    }
    int iis = (w & 1)*16 + lg*4;
    #pragma unroll
    for (int bf_ = 0; bf_ < 2; ++bf_) {
      #pragma unroll
      for (int rg = 0; rg < 4; ++rg) {
        int ssu = bf_*16 + lr;
        float v = (bf_ < nb_ && ssu < iis + rg) ? dgc[bf_][rg] : 0.f;
        dgs[w][(lg*4 + rg)*40 + bf_*16 + lr] = f2bf(v);
      }
    }
    FB dga;
    dga.u = *(const uint4*)&dgs[w][lr*40 + ks];
    #pragma unroll
    for (int nf = 0; nf < 4; ++nf) {
      FB vv;
      vv.u = *(const uint4*)&vT[(nf*16+lr)*72 + T + ks];
      acc[nf] = __builtin_amdgcn_mfma_f32_16x16x32_bf16(dga.h, vv.h, acc[nf], 0,0,0);
    }
  }

  // ---- store ----
  #pragma unroll
  for (int nf = 0; nf < 4; ++nf)
    #pragma unroll
    for (int rg = 0; rg < 4; ++rg)
      outp[(rowbase + w*16 + lg*4 + rg)*DIMN + colbase + nf*16 + lr] = acc[nf][rg];
}

extern "C" void kernel_launch(void* const* d_in, const int* in_sizes, int n_in,
                              void* d_out, int out_size, void* d_ws, size_t ws_size,
                              hipStream_t stream) {
  const float* x   = (const float*)d_in[0];
  const float* Wq  = (const float*)d_in[1];
  const float* bq  = (const float*)d_in[2];
  const float* Wk  = (const float*)d_in[3];
  const float* bk  = (const float*)d_in[4];
  const float* Wv  = (const float*)d_in[5];
  const float* bv  = (const float*)d_in[6];
  const float* Wg1 = (const float*)d_in[7];
  const float* bg1 = (const float*)d_in[8];
  const float* Wg2 = (const float*)d_in[9];
  const float* bg2 = (const float*)d_in[10];
  float* out = (float*)d_out;

  float* ws = (float*)d_ws;
  const size_t NT = (size_t)NTOK*DIMN;  // 4194304
  const size_t NST = (size_t)NB*NH*NCHUNK*HD*HD;         // 4194304
  float* hid = ws;                                       // 65536 f32
  float* Bv  = hid + (size_t)NTOK*GH;                    // 65536 f32
  unsigned short* stb = (unsigned short*)(Bv + (size_t)NB*NH*NCHUNK*HD); // bf16 G->states
  unsigned short* xb = stb + NST;
  unsigned short* wt = xb + NT;                          // [3072][1024] bf16
  unsigned short* wg1b = wt + 3*(size_t)DIMN*DIMN;       // 16x1024 bf16
  unsigned short* qb = wg1b + (size_t)GH*DIMN;           // bf16 q/k/v
  unsigned short* kb = qb + NT;
  unsigned short* vb = kb + NT;

  k_cast_wT<<<dim3(16, 16, 3), 256, 0, stream>>>(Wq, Wk, Wv, wt);
  k_wg1t<<<(GH*DIMN)/256, 256, 0, stream>>>(Wg1, wg1b);
  k_castx_hidden<<<NTOK/16, 256, 0, stream>>>(x, wg1b, bg1, xb, hid);
  k_projqkv<<<dim3(24, 32), 256, 0, stream>>>(
      xb, wt, bq, bk, bv, qb, kb, vb);
  k_ginc<<<NB*NH*NCHUNK, 256, 0, stream>>>(kb, vb, hid, Wg2, bg2, stb, Bv);
  k_scan<<<(NB*NH*HD*HD)/256, 256, 0, stream>>>(stb, Bv);
  k_chunk<<<NB*NH*NCHUNK, 256, 0, stream>>>(qb, kb, vb, hid, Wg2, bg2, stb, out);
}

// Round 15
// 93.168 us; speedup vs baseline: 1.0375x; 1.0121x over previous
//
#include <hip/hip_runtime.h>
#include <math.h>

#define DIMN 1024
#define NH 16
#define HD 64
#define CHK 64
#define NB 2
#define SEQ 2048
#define NTOK (NB*SEQ)        // 4096
#define NCHUNK (SEQ/CHK)     // 32
#define GH 16

typedef __bf16 bf16x8 __attribute__((ext_vector_type(8)));
typedef float f32x4 __attribute__((ext_vector_type(4)));
typedef unsigned short u16x4 __attribute__((ext_vector_type(4)));

__device__ __forceinline__ unsigned short f2bf(float f) {
  union { float f; unsigned u; } a; a.f = f;
  unsigned r = a.u + 0x7FFFu + ((a.u >> 16) & 1u);
  return (unsigned short)(r >> 16);
}
__device__ __forceinline__ float bf2f(unsigned short v) {
  union { unsigned u; float f; } a; a.u = ((unsigned)v) << 16;
  return a.f;
}

__device__ __forceinline__ void gload16(const void* g, void* l) {
  __builtin_amdgcn_global_load_lds(
      (const __attribute__((address_space(1))) void*)g,
      (__attribute__((address_space(3))) void*)l, 16, 0, 0);
}

// ---- cast + transpose W (K x N f32) -> Wt (N x K bf16), LDS-tiled 64x64 ----
__global__ __launch_bounds__(256) void k_cast_wT(const float* __restrict__ W0,
    const float* __restrict__ W1, const float* __restrict__ W2,
    unsigned short* __restrict__ wt) {
  __shared__ float tile[64][68];
  int z = blockIdx.z;
  const float* W = z==0 ? W0 : z==1 ? W1 : W2;
  unsigned short* o = wt + (size_t)z*DIMN*DIMN;
  int k0 = blockIdx.y*64, n0 = blockIdx.x*64;
  int tr = threadIdx.x >> 4, c0 = (threadIdx.x & 15)*4;
  #pragma unroll
  for (int s = 0; s < 4; ++s) {
    int r = tr + s*16;
    *(f32x4*)&tile[r][c0] = *(const f32x4*)(W + (size_t)(k0+r)*DIMN + n0 + c0);
  }
  __syncthreads();
  #pragma unroll
  for (int s = 0; s < 4; ++s) {
    int nn = tr + s*16;
    ushort4 v;
    v.x = f2bf(tile[c0+0][nn]);
    v.y = f2bf(tile[c0+1][nn]);
    v.z = f2bf(tile[c0+2][nn]);
    v.w = f2bf(tile[c0+3][nn]);
    *(ushort4*)(o + (size_t)(n0+nn)*DIMN + k0 + c0) = v;
  }
}

// ---------------- transpose+cast Wg1 (1024x16 f32) -> wg1b (16x1024 bf16) ---
__global__ __launch_bounds__(256) void k_wg1t(const float* __restrict__ Wg1,
    unsigned short* __restrict__ wg1b) {
  int idx = blockIdx.x*256 + threadIdx.x;     // 16384
  int k = idx & 1023, j = idx >> 10;
  wg1b[j*DIMN + k] = f2bf(Wg1[k*GH + j]);
}

// ---- fused: cast x->bf16 (16-row tile via LDS) + hid = silu(xb@wg1b^T+bg1) --
__global__ __launch_bounds__(256) void k_castx_hidden(const float* __restrict__ x,
    const unsigned short* __restrict__ wg1b, const float* __restrict__ bg1,
    unsigned short* __restrict__ xb, float* __restrict__ hid) {
  __shared__ __align__(16) unsigned short xs[16][1032];  // pad: 2-way bank alias (free)
  __shared__ float red[4][16][16];
  int tid = threadIdx.x;
  size_t base = (size_t)blockIdx.x * 16 * DIMN;
  #pragma unroll
  for (int i = 0; i < 16; ++i) {
    int idx4 = tid + i*256;            // f32x4 index in tile, 0..4095
    int r = idx4 >> 8, c4 = idx4 & 255;
    f32x4 v = *(const f32x4*)(x + base + (size_t)idx4*4);
    u16x4 o;
    o[0]=f2bf(v[0]); o[1]=f2bf(v[1]); o[2]=f2bf(v[2]); o[3]=f2bf(v[3]);
    *(u16x4*)&xs[r][c4*4] = o;
    *(u16x4*)(xb + base + (size_t)idx4*4) = o;
  }
  __syncthreads();
  int l = tid & 63, w = tid >> 6;
  int lr = l & 15, kg = l >> 4;
  union FB { uint4 u; bf16x8 h; } a, b;
  f32x4 acc = {0.f,0.f,0.f,0.f};
  const unsigned short* wrow = wg1b + (size_t)lr*DIMN + w*256 + kg*8;
  #pragma unroll
  for (int kk = 0; kk < 8; ++kk) {
    a.u = *(const uint4*)&xs[lr][w*256 + kk*32 + kg*8];
    b.u = *(const uint4*)(wrow + kk*32);
    acc = __builtin_amdgcn_mfma_f32_16x16x32_bf16(a.h, b.h, acc, 0, 0, 0);
  }
  #pragma unroll
  for (int rg = 0; rg < 4; ++rg) red[w][kg*4 + rg][lr] = acc[rg];
  __syncthreads();
  {
    int m = tid >> 4, j = tid & 15;
    float s = red[0][m][j] + red[1][m][j] + red[2][m][j] + red[3][m][j];
    s += bg1[j];
    hid[(blockIdx.x*16 + m)*GH + j] = s / (1.f + expf(-s));   // silu
  }
}

// ---------------- fused bf16 MFMA projection: {q,k,v} = x @ [Wq|Wk|Wv] + b --
// 3-buffer LDS rotation, 2-deep prefetch, counted vmcnt + raw s_barrier (T4).
__global__ __launch_bounds__(256, 3) void k_projqkv(const unsigned short* __restrict__ xb,
    const unsigned short* __restrict__ wt,
    const float* __restrict__ b0, const float* __restrict__ b1, const float* __restrict__ b2,
    unsigned short* __restrict__ o0, unsigned short* __restrict__ o1,
    unsigned short* __restrict__ o2) {
  __shared__ unsigned short As[3][128*32];
  __shared__ unsigned short Bs[3][128*32];
  int tid = threadIdx.x;
  int wg = blockIdx.y * gridDim.x + blockIdx.x;   // 0..767 (768 % 8 == 0)
  int swz = (wg & 7) * 96 + (wg >> 3);
  int bx = swz % 24, by = swz / 24;
  int n3 = bx*128;
  int z = n3 >> 10;
  int n0l = n3 & 1023;
  const float* bias = z==0 ? b0 : z==1 ? b1 : b2;
  unsigned short* out = z==0 ? o0 : z==1 ? o1 : o2;
  int m0 = by*128;

  int l = tid & 63;
  int w = tid >> 6;
  int wr = w >> 1, wc = w & 1;
  int lrow = l & 15, kg = l >> 4;

  f32x4 acc[4][4] = {};

  int r0s = tid >> 2, s0s = tid & 3;
  int r1s = (tid + 256) >> 2;
  int sg0 = s0s ^ ((r0s >> 1) & 3);
  int sg1 = s0s ^ ((r1s >> 1) & 3);

  #define STAGE(buf, kt) do { \
    int kb_ = (kt)*32; \
    gload16(xb + ((size_t)(m0 + r0s)*DIMN + kb_ + sg0*8), &As[buf][tid*8]); \
    gload16(wt + ((size_t)(n3 + r0s)*DIMN + kb_ + sg0*8), &Bs[buf][tid*8]); \
    gload16(xb + ((size_t)(m0 + r1s)*DIMN + kb_ + sg1*8), &As[buf][(tid+256)*8]); \
    gload16(wt + ((size_t)(n3 + r1s)*DIMN + kb_ + sg1*8), &Bs[buf][(tid+256)*8]); \
  } while (0)

  STAGE(0, 0);
  STAGE(1, 1);
  for (int t = 0; t < DIMN/32; ++t) {
    if (t < DIMN/32 - 1) {
      asm volatile("s_waitcnt vmcnt(4)" ::: "memory");   // tile t resident (own loads)
    } else {
      asm volatile("s_waitcnt vmcnt(0)" ::: "memory");   // final tile
    }
    __builtin_amdgcn_s_barrier();                        // all waves confirmed tile t
    if (t+2 < DIMN/32) STAGE((t+2)%3, t+2);              // overwrite buf read at t-1
    int buf = t % 3;
    union { uint4 u; bf16x8 h; } af[4], bfr[4];
    #pragma unroll
    for (int mf = 0; mf < 4; ++mf) {
      int r = wr*64 + mf*16 + lrow;
      int slot = kg ^ ((r >> 1) & 3);
      af[mf].u = *(const uint4*)&As[buf][r*32 + slot*8];
    }
    #pragma unroll
    for (int nf = 0; nf < 4; ++nf) {
      int r = wc*64 + nf*16 + lrow;
      int slot = kg ^ ((r >> 1) & 3);
      bfr[nf].u = *(const uint4*)&Bs[buf][r*32 + slot*8];
    }
    #pragma unroll
    for (int mf = 0; mf < 4; ++mf)
      #pragma unroll
      for (int nf = 0; nf < 4; ++nf)
        acc[mf][nf] = __builtin_amdgcn_mfma_f32_16x16x32_bf16(
            af[mf].h, bfr[nf].h, acc[mf][nf], 0, 0, 0);
  }
  #undef STAGE

  float bv[4];
  #pragma unroll
  for (int nf = 0; nf < 4; ++nf) bv[nf] = bias[n0l + wc*64 + nf*16 + lrow];
  #pragma unroll
  for (int mf = 0; mf < 4; ++mf) {
    int rbase = m0 + wr*64 + mf*16 + kg*4;
    #pragma unroll
    for (int nf = 0; nf < 4; ++nf) {
      int c = n0l + wc*64 + nf*16 + lrow;
      #pragma unroll
      for (int rg = 0; rg < 4; ++rg)
        out[(size_t)(rbase+rg)*DIMN + c] = f2bf(acc[mf][nf][rg] + bv[nf]);
    }
  }
}

// ---------------- pass 1a: per-chunk increment G_n via MFMA -----------------
__global__ __launch_bounds__(256, 4) void k_ginc(const unsigned short* __restrict__ kbuf,
    const unsigned short* __restrict__ vbuf,
    const float* __restrict__ hid, const float* __restrict__ Wg2,
    const float* __restrict__ bg2,
    unsigned short* __restrict__ G, float* __restrict__ Bv) {
  __shared__ __align__(16) unsigned short kb16[64*72];   // [i][d]
  __shared__ __align__(16) unsigned short vT[64*72];     // [e][i]
  __shared__ __align__(16) unsigned short kdT[64*72];    // [d][i]
  __shared__ __align__(16) float scr[2048];              // hid tile | Wg2 slice
  __shared__ float seg[4][64];
  int tid = threadIdx.x;
  int bid = blockIdx.x;                 // bh*NCHUNK + n
  int bh = bid >> 5, n = bid & 31;
  int b = bh >> 4, h = bh & 15;
  int colbase = h*HD;
  size_t rowbase = (size_t)b*SEQ + n*CHK;

  {
    int r = tid >> 2, j0 = (tid & 3)*4;
    *(f32x4*)&scr[r*16 + j0] = *(const f32x4*)(hid + (rowbase + r)*GH + j0);
    int j = tid >> 4, d0 = (tid & 15)*4;
    *(f32x4*)&scr[1024 + j*64 + d0] = *(const f32x4*)(Wg2 + (size_t)j*DIMN + colbase + d0);
  }
  #pragma unroll
  for (int i = 0; i < 4; ++i) {
    int f4 = tid + i*256;
    int r = f4 >> 4, cg = f4 & 15, c0 = cg*4;
    size_t g = (rowbase + r)*DIMN + colbase + c0;
    u16x4 k4 = *(const u16x4*)(kbuf + g);
    u16x4 v4 = *(const u16x4*)(vbuf + g);
    *(u16x4*)&kb16[r*72 + c0] = k4;
    #pragma unroll
    for (int j = 0; j < 4; ++j) vT[(c0+j)*72 + r] = v4[j];
  }
  __syncthreads();

  {
    int d = tid & 63, ig = tid >> 6;
    float wcol[16];
    #pragma unroll
    for (int j = 0; j < 16; ++j) wcol[j] = scr[1024 + j*64 + d];
    float bgd = bg2[colbase + d];
    float P[16];
    float run = 0.f;
    #pragma unroll
    for (int t = 0; t < 16; ++t) {
      int i = ig*16 + t;
      float acc = bgd;
      #pragma unroll
      for (int j = 0; j < 16; ++j) acc = fmaf(scr[i*16 + j], wcol[j], acc);
      float gg = 1.f/(1.f + expf(-acc));
      run += log2f(fmaf(0.9f, gg, 0.1f));
      P[t] = run;
    }
    seg[ig][d] = run;
    __syncthreads();
    float s0 = seg[0][d], s1 = seg[1][d], s2 = seg[2][d], s3 = seg[3][d];
    float carry = (ig > 0 ? s0 : 0.f) + (ig > 1 ? s1 : 0.f) + (ig > 2 ? s2 : 0.f);
    float Lb63 = s0 + s1 + s2 + s3;
    if (ig == 0) Bv[(size_t)bid*HD + d] = exp2f(Lb63);
    union { unsigned short s[16]; uint4 u[2]; } kd;
    #pragma unroll
    for (int t = 0; t < 16; ++t) {
      int i = ig*16 + t;
      float kv = bf2f(kb16[i*72 + d]);
      kd.s[t] = f2bf(kv * exp2f(Lb63 - carry - P[t]));   // suffix decay
    }
    *(uint4*)&kdT[d*72 + ig*16] = kd.u[0];
    *(uint4*)&kdT[d*72 + ig*16 + 8] = kd.u[1];
  }
  __syncthreads();

  int l = tid & 63, w = tid >> 6;
  int lr = l & 15, kg = l >> 4;
  int ks = kg*8;
  int arow = w*16 + lr;
  union FB { uint4 u; bf16x8 h; } a0, a1;
  a0.u = *(const uint4*)&kdT[arow*72 + ks];
  a1.u = *(const uint4*)&kdT[arow*72 + 32 + ks];
  unsigned short* gp = G + (size_t)bid*(HD*HD);
  #pragma unroll
  for (int nf = 0; nf < 4; ++nf) {
    FB b0v, b1v;
    b0v.u = *(const uint4*)&vT[(nf*16+lr)*72 + ks];
    b1v.u = *(const uint4*)&vT[(nf*16+lr)*72 + 32 + ks];
    f32x4 z = {0.f,0.f,0.f,0.f};
    z = __builtin_amdgcn_mfma_f32_16x16x32_bf16(a0.h, b0v.h, z, 0,0,0);
    z = __builtin_amdgcn_mfma_f32_16x16x32_bf16(a1.h, b1v.h, z, 0,0,0);
    #pragma unroll
    for (int rg = 0; rg < 4; ++rg)
      gp[(w*16 + kg*4 + rg)*HD + nf*16 + lr] = f2bf(z[rg]);
  }
}

// ---- pass 1b (parallel scan): preload-all then in-place bf16 G -> states ---
__global__ __launch_bounds__(256) void k_scan(unsigned short* __restrict__ buf,
    const float* __restrict__ Bv) {
  int idx = blockIdx.x*256 + threadIdx.x;   // 131072 = 32*64*64
  int e = idx & 63, d = (idx >> 6) & 63, bh = idx >> 12;
  unsigned short* gp = buf + (size_t)bh*NCHUNK*HD*HD + d*HD + e;
  const float* bp = Bv + (size_t)bh*NCHUNK*HD + d;
  float g[NCHUNK], bb[NCHUNK];
  #pragma unroll
  for (int n = 0; n < NCHUNK; ++n) g[n] = bf2f(gp[n*(HD*HD)]);
  #pragma unroll
  for (int n = 0; n < NCHUNK; ++n) bb[n] = bp[n*HD];
  float s = 0.f;
  #pragma unroll
  for (int n = 0; n < NCHUNK; ++n) {
    gp[n*(HD*HD)] = f2bf(s);
    s = fmaf(bb[n], s, g[n]);
  }
}

// ---------------- pass 2: MFMA per-chunk intra softmax + inter (sub=32) -----
// R13 structure + merged alpha/prefix (one reg pass, proven in R12) + T5
// setprio around MFMA clusters (2 independent blocks/CU = m191 regime).
__global__ __launch_bounds__(256) void k_chunk(const unsigned short* __restrict__ qbuf,
    const unsigned short* __restrict__ kbuf, const unsigned short* __restrict__ vbuf,
    const float* __restrict__ hid, const float* __restrict__ Wg2,
    const float* __restrict__ bg2,
    const unsigned short* __restrict__ states, float* __restrict__ outp) {
  __shared__ __align__(16) unsigned short qb16[64*72];
  __shared__ __align__(16) unsigned short kb16[64*72];
  __shared__ __align__(16) unsigned short vT[64*72];     // [e][s]
  __shared__ __align__(16) unsigned short Pl[64*72];     // [i][s]; early: hid scratch
  __shared__ __align__(16) unsigned short Swt[2][64*72]; // [e][d] states (T=0, T=32)
  __shared__ __align__(16) float lb[65*68];              // [i][d] excl prefix log2(alpha)
  __shared__ __align__(16) unsigned short dgs[4][16*40]; // per-wave dg A staging
  __shared__ float seg[4][64];

  const int tid = threadIdx.x;
  const int bid = blockIdx.x;
  const int bh = bid >> 5, n = bid & 31;
  const int b = bh >> 4, h = bh & 15;
  const int colbase = h*HD;
  const size_t rowbase = (size_t)b*SEQ + n*CHK;
  const unsigned short* stp = states + (size_t)(bh*NCHUNK + n)*(HD*HD);

  float* scr = (float*)Pl;   // [0..1023] = hid tile
  {
    int r = tid >> 2, j0 = (tid & 3)*4;
    *(f32x4*)&scr[r*16 + j0] = *(const f32x4*)(hid + (rowbase + r)*GH + j0);
  }
  #pragma unroll
  for (int i = 0; i < 4; ++i) {
    int f4 = tid + i*256;
    int r = f4 >> 4, cg = f4 & 15, c0 = cg*4;
    size_t g = (rowbase + r)*DIMN + colbase + c0;
    u16x4 q4 = *(const u16x4*)(qbuf + g);
    u16x4 k4 = *(const u16x4*)(kbuf + g);
    u16x4 v4 = *(const u16x4*)(vbuf + g);
    u16x4 s4 = *(const u16x4*)(stp + r*HD + c0);
    #pragma unroll
    for (int j = 0; j < 4; ++j) {
      vT[(c0+j)*72 + r] = v4[j];
      Swt[0][(c0+j)*72 + r] = s4[j];
    }
    *(u16x4*)&qb16[r*72 + c0] = q4;
    *(u16x4*)&kb16[r*72 + c0] = k4;
  }
  __syncthreads();

  // ---- merged alpha + exclusive prefix (thread owns (d, ig)) ----
  {
    int d = tid & 63, ig = tid >> 6;
    float wcol[16];
    #pragma unroll
    for (int j = 0; j < 16; ++j) wcol[j] = Wg2[(size_t)j*DIMN + colbase + d];
    float bgd = bg2[colbase + d];
    float Pex[16];
    float run = 0.f;
    #pragma unroll
    for (int t = 0; t < 16; ++t) {
      int i = ig*16 + t;
      float acc = bgd;
      #pragma unroll
      for (int j = 0; j < 16; ++j) acc = fmaf(scr[i*16 + j], wcol[j], acc);
      float gg = 1.f/(1.f + expf(-acc));
      Pex[t] = run;
      run += log2f(fmaf(0.9f, gg, 0.1f));
    }
    seg[ig][d] = run;
    __syncthreads();
    float carry = 0.f;
    for (int w2 = 0; w2 < ig; ++w2) carry += seg[w2][d];
    #pragma unroll
    for (int t = 0; t < 16; ++t)
      lb[(ig*16 + t)*68 + d] = carry + Pex[t];
    if (ig == 3) lb[64*68 + d] = carry + run;
  }
  __syncthreads();           // lb complete; scr (Pl alias) dead from here

  const int l = tid & 63, w = tid >> 6;
  const int lr = l & 15, lg = l >> 4;
  const int ks = lg*8;
  const int arow = w*16 + lr;

  union FB { uint4 u; bf16x8 h; unsigned short s[8]; };

  // ---- QK^T (MFMA) ----
  FB qa0, qa1;
  qa0.u = *(const uint4*)&qb16[arow*72 + ks];
  qa1.u = *(const uint4*)&qb16[arow*72 + 32 + ks];
  f32x4 sc[4];
  __builtin_amdgcn_s_setprio(1);
  #pragma unroll
  for (int nf = 0; nf < 4; ++nf) {
    FB b0, b1;
    b0.u = *(const uint4*)&kb16[(nf*16+lr)*72 + ks];
    b1.u = *(const uint4*)&kb16[(nf*16+lr)*72 + 32 + ks];
    f32x4 z = {0.f,0.f,0.f,0.f};
    z = __builtin_amdgcn_mfma_f32_16x16x32_bf16(qa0.h, b0.h, z, 0,0,0);
    z = __builtin_amdgcn_mfma_f32_16x16x32_bf16(qa1.h, b1.h, z, 0,0,0);
    sc[nf] = z;
  }
  __builtin_amdgcn_s_setprio(0);

  // ---- in-register causal softmax ----
  float rmax[4] = {-3e38f,-3e38f,-3e38f,-3e38f};
  #pragma unroll
  for (int nf = 0; nf < 4; ++nf) {
    int col = nf*16 + lr;
    #pragma unroll
    for (int rg = 0; rg < 4; ++rg) {
      int row = w*16 + lg*4 + rg;
      float v = sc[nf][rg]*0.125f;
      if (col > row) v = -1e30f;
      sc[nf][rg] = v;
      rmax[rg] = fmaxf(rmax[rg], v);
    }
  }
  #pragma unroll
  for (int m = 1; m <= 8; m <<= 1)
    #pragma unroll
    for (int rg = 0; rg < 4; ++rg)
      rmax[rg] = fmaxf(rmax[rg], __shfl_xor(rmax[rg], m));
  float rsum[4] = {0.f,0.f,0.f,0.f};
  #pragma unroll
  for (int nf = 0; nf < 4; ++nf)
    #pragma unroll
    for (int rg = 0; rg < 4; ++rg) {
      float e = exp2f((sc[nf][rg] - rmax[rg])*1.44269504f);
      sc[nf][rg] = e;
      rsum[rg] += e;
    }
  #pragma unroll
  for (int m = 1; m <= 8; m <<= 1)
    #pragma unroll
    for (int rg = 0; rg < 4; ++rg)
      rsum[rg] += __shfl_xor(rsum[rg], m);
  // scr (Pl) dead since post-prefix barrier; disjoint Pl writes are safe now
  #pragma unroll
  for (int nf = 0; nf < 4; ++nf)
    #pragma unroll
    for (int rg = 0; rg < 4; ++rg)
      Pl[(w*16 + lg*4 + rg)*72 + nf*16 + lr] = f2bf(sc[nf][rg]);
  float inv[4];
  #pragma unroll
  for (int rg = 0; rg < 4; ++rg) inv[rg] = 1.f/rsum[rg];
  __syncthreads();

  // ---- intra = P@V / rowsum (MFMA) ----
  f32x4 acc[4];
  {
    FB p0, p1;
    p0.u = *(const uint4*)&Pl[arow*72 + ks];
    p1.u = *(const uint4*)&Pl[arow*72 + 32 + ks];
    __builtin_amdgcn_s_setprio(1);
    #pragma unroll
    for (int nf = 0; nf < 4; ++nf) {
      FB v0, v1;
      v0.u = *(const uint4*)&vT[(nf*16+lr)*72 + ks];
      v1.u = *(const uint4*)&vT[(nf*16+lr)*72 + 32 + ks];
      f32x4 z = {0.f,0.f,0.f,0.f};
      z = __builtin_amdgcn_mfma_f32_16x16x32_bf16(p0.h, v0.h, z, 0,0,0);
      z = __builtin_amdgcn_mfma_f32_16x16x32_bf16(p1.h, v1.h, z, 0,0,0);
      #pragma unroll
      for (int rg = 0; rg < 4; ++rg)
        acc[nf][rg] = z[rg]*inv[rg];
    }
    __builtin_amdgcn_s_setprio(0);
  }

  // ---- state update: S1 = diag(exp2(lb32)) S0 + sum_{s<32} kupd_s v_s^T ----
  {
    int dA = arow;
    float lb32 = lb[32*68 + dA];
    FB ku;
    #pragma unroll
    for (int j = 0; j < 8; ++j) {
      int s = ks + j;
      float kv = bf2f(kb16[s*72 + dA]);
      ku.s[j] = f2bf(kv * exp2f(lb32 - lb[(s+1)*68 + dA]));
    }
    int d0 = w*16 + lg*4;
    float bs[4];
    #pragma unroll
    for (int rg = 0; rg < 4; ++rg) bs[rg] = exp2f(lb[32*68 + d0 + rg]);
    __builtin_amdgcn_s_setprio(1);
    #pragma unroll
    for (int nf = 0; nf < 4; ++nf) {
      int e = nf*16 + lr;
      FB vv;
      vv.u = *(const uint4*)&vT[e*72 + ks];
      f32x4 z = {0.f,0.f,0.f,0.f};
      z = __builtin_amdgcn_mfma_f32_16x16x32_bf16(ku.h, vv.h, z, 0,0,0);
      u16x4 s0v = *(const u16x4*)&Swt[0][e*72 + d0];
      u16x4 s1v;
      #pragma unroll
      for (int rg = 0; rg < 4; ++rg)
        s1v[rg] = f2bf(z[rg] + bs[rg]*bf2f(s0v[rg]));
      *(u16x4*)&Swt[1][e*72 + d0] = s1v;
    }
    __builtin_amdgcn_s_setprio(0);
  }
  __syncthreads();

  // ---- inter: cross (qdec @ S_T^T) + strict-lower diag, per wave ----
  {
    const int T = (w >= 2) ? 32 : 0;
    const unsigned short* Ssel = (w >= 2) ? &Swt[1][0] : &Swt[0][0];
    FB qd[2];
    #pragma unroll
    for (int kst = 0; kst < 2; ++kst) {
      int ds = kst*32 + ks;
      f32x4 lbi0 = *(const f32x4*)&lb[arow*68 + ds];
      f32x4 lbi1 = *(const f32x4*)&lb[arow*68 + ds + 4];
      f32x4 lbt0 = *(const f32x4*)&lb[T*68 + ds];
      f32x4 lbt1 = *(const f32x4*)&lb[T*68 + ds + 4];
      FB qr;
      qr.u = *(const uint4*)&qb16[arow*72 + ds];
      #pragma unroll
      for (int j = 0; j < 4; ++j) {
        qd[kst].s[j]   = f2bf(bf2f(qr.s[j])   * exp2f(lbi0[j] - lbt0[j]));
        qd[kst].s[4+j] = f2bf(bf2f(qr.s[4+j]) * exp2f(lbi1[j] - lbt1[j]));
      }
    }
    __builtin_amdgcn_s_setprio(1);
    #pragma unroll
    for (int nf = 0; nf < 4; ++nf) {
      FB s0f, s1f;
      s0f.u = *(const uint4*)&Ssel[(nf*16+lr)*72 + ks];
      s1f.u = *(const uint4*)&Ssel[(nf*16+lr)*72 + 32 + ks];
      acc[nf] = __builtin_amdgcn_mfma_f32_16x16x32_bf16(qd[0].h, s0f.h, acc[nf], 0,0,0);
      acc[nf] = __builtin_amdgcn_mfma_f32_16x16x32_bf16(qd[1].h, s1f.h, acc[nf], 0,0,0);
    }
    __builtin_amdgcn_s_setprio(0);
    const int nb_ = (w & 1) ? 2 : 1;
    f32x4 dgc[2] = {{0.f,0.f,0.f,0.f},{0.f,0.f,0.f,0.f}};
    #pragma unroll
    for (int bf_ = 0; bf_ < 2; ++bf_) {
      if (bf_ < nb_) {
        int s = T + bf_*16 + lr;
        f32x4 z = {0.f,0.f,0.f,0.f};
        #pragma unroll
        for (int kst = 0; kst < 2; ++kst) {
          int ds = kst*32 + ks;
          f32x4 lbt0 = *(const f32x4*)&lb[T*68 + ds];
          f32x4 lbt1 = *(const f32x4*)&lb[T*68 + ds + 4];
          f32x4 lbs0 = *(const f32x4*)&lb[(s+1)*68 + ds];
          f32x4 lbs1 = *(const f32x4*)&lb[(s+1)*68 + ds + 4];
          FB kr, kd;
          kr.u = *(const uint4*)&kb16[s*72 + ds];
          #pragma unroll
          for (int j = 0; j < 4; ++j) {
            kd.s[j]   = f2bf(bf2f(kr.s[j])   * exp2f(lbt0[j] - lbs0[j]));
            kd.s[4+j] = f2bf(bf2f(kr.s[4+j]) * exp2f(lbt1[j] - lbs1[j]));
          }
          z = __builtin_amdgcn_mfma_f32_16x16x32_bf16(qd[kst].h, kd.h, z, 0,0,0);
        }
        dgc[bf_] = z;
      }
    }
    int iis = (w & 1)*16 + lg*4;
    #pragma unroll
    for (int bf_ = 0; bf_ < 2; ++bf_) {
      #pragma unroll
      for (int rg = 0; rg < 4; ++rg) {
        int ssu = bf_*16 + lr;
        float v = (bf_ < nb_ && ssu < iis + rg) ? dgc[bf_][rg] : 0.f;
        dgs[w][(lg*4 + rg)*40 + bf_*16 + lr] = f2bf(v);
      }
    }
    FB dga;
    dga.u = *(const uint4*)&dgs[w][lr*40 + ks];
    __builtin_amdgcn_s_setprio(1);
    #pragma unroll
    for (int nf = 0; nf < 4; ++nf) {
      FB vv;
      vv.u = *(const uint4*)&vT[(nf*16+lr)*72 + T + ks];
      acc[nf] = __builtin_amdgcn_mfma_f32_16x16x32_bf16(dga.h, vv.h, acc[nf], 0,0,0);
    }
    __builtin_amdgcn_s_setprio(0);
  }

  // ---- store ----
  #pragma unroll
  for (int nf = 0; nf < 4; ++nf)
    #pragma unroll
    for (int rg = 0; rg < 4; ++rg)
      outp[(rowbase + w*16 + lg*4 + rg)*DIMN + colbase + nf*16 + lr] = acc[nf][rg];
}

extern "C" void kernel_launch(void* const* d_in, const int* in_sizes, int n_in,
                              void* d_out, int out_size, void* d_ws, size_t ws_size,
                              hipStream_t stream) {
  const float* x   = (const float*)d_in[0];
  const float* Wq  = (const float*)d_in[1];
  const float* bq  = (const float*)d_in[2];
  const float* Wk  = (const float*)d_in[3];
  const float* bk  = (const float*)d_in[4];
  const float* Wv  = (const float*)d_in[5];
  const float* bv  = (const float*)d_in[6];
  const float* Wg1 = (const float*)d_in[7];
  const float* bg1 = (const float*)d_in[8];
  const float* Wg2 = (const float*)d_in[9];
  const float* bg2 = (const float*)d_in[10];
  float* out = (float*)d_out;

  float* ws = (float*)d_ws;
  const size_t NT = (size_t)NTOK*DIMN;  // 4194304
  const size_t NST = (size_t)NB*NH*NCHUNK*HD*HD;         // 4194304
  float* hid = ws;                                       // 65536 f32
  float* Bv  = hid + (size_t)NTOK*GH;                    // 65536 f32
  unsigned short* stb = (unsigned short*)(Bv + (size_t)NB*NH*NCHUNK*HD); // bf16 G->states
  unsigned short* xb = stb + NST;
  unsigned short* wt = xb + NT;                          // [3072][1024] bf16
  unsigned short* wg1b = wt + 3*(size_t)DIMN*DIMN;       // 16x1024 bf16
  unsigned short* qb = wg1b + (size_t)GH*DIMN;           // bf16 q/k/v
  unsigned short* kb = qb + NT;
  unsigned short* vb = kb + NT;

  k_cast_wT<<<dim3(16, 16, 3), 256, 0, stream>>>(Wq, Wk, Wv, wt);
  k_wg1t<<<(GH*DIMN)/256, 256, 0, stream>>>(Wg1, wg1b);
  k_castx_hidden<<<NTOK/16, 256, 0, stream>>>(x, wg1b, bg1, xb, hid);
  k_projqkv<<<dim3(24, 32), 256, 0, stream>>>(
      xb, wt, bq, bk, bv, qb, kb, vb);
  k_ginc<<<NB*NH*NCHUNK, 256, 0, stream>>>(kb, vb, hid, Wg2, bg2, stb, Bv);
  k_scan<<<(NB*NH*HD*HD)/256, 256, 0, stream>>>(stb, Bv);
  k_chunk<<<NB*NH*NCHUNK, 256, 0, stream>>>(qb, kb, vb, hid, Wg2, bg2, stb, out);
}